// Round 7
// baseline (352.089 us; speedup 1.0000x reference)
//
#include <hip/hip_runtime.h>
#include <hip/hip_bf16.h>

#define Bn 2
#define Tn 2048
#define Cn 1024
#define Hn 16
#define Dn 64
#define Mrows (Bn * Tn)   // 4096

typedef __attribute__((ext_vector_type(8))) short short8;
typedef __attribute__((ext_vector_type(4))) float f32x4;

typedef const __attribute__((address_space(1))) unsigned int* gas_ptr;
typedef __attribute__((address_space(3))) unsigned int* las_ptr;

__device__ __forceinline__ unsigned short f2b(float f) {
  unsigned int u = __builtin_bit_cast(unsigned int, f);
  return (unsigned short)((u + 0x7fffu + ((u >> 16) & 1u)) >> 16);
}

// ---------------- LayerNorm: f32 in -> bf16 out ----------------
__global__ __launch_bounds__(256) void ln_kernel(const float* __restrict__ x,
                                                 const float* __restrict__ w,
                                                 const float* __restrict__ b,
                                                 unsigned short* __restrict__ out) {
  const int row = blockIdx.x;
  const int t = threadIdx.x;
  const float4 v = *reinterpret_cast<const float4*>(x + (size_t)row * Cn + t * 4);
  float s = v.x + v.y + v.z + v.w;
  float s2 = v.x * v.x + v.y * v.y + v.z * v.z + v.w * v.w;
#pragma unroll
  for (int m = 1; m < 64; m <<= 1) { s += __shfl_xor(s, m); s2 += __shfl_xor(s2, m); }
  __shared__ float ls[4], ls2[4];
  if ((t & 63) == 0) { ls[t >> 6] = s; ls2[t >> 6] = s2; }
  __syncthreads();
  s  = ls[0] + ls[1] + ls[2] + ls[3];
  s2 = ls2[0] + ls2[1] + ls2[2] + ls2[3];
  const float mu = s * (1.0f / Cn);
  const float rstd = rsqrtf(s2 * (1.0f / Cn) - mu * mu + 1e-5f);
  const float4 wv = *reinterpret_cast<const float4*>(w + t * 4);
  const float4 bv = *reinterpret_cast<const float4*>(b + t * 4);
  unsigned short o[4];
  o[0] = f2b((v.x - mu) * rstd * wv.x + bv.x);
  o[1] = f2b((v.y - mu) * rstd * wv.y + bv.y);
  o[2] = f2b((v.z - mu) * rstd * wv.z + bv.z);
  o[3] = f2b((v.w - mu) * rstd * wv.w + bv.w);
  *reinterpret_cast<uint2*>(out + (size_t)row * Cn + t * 4) = *reinterpret_cast<uint2*>(o);
}

// ---------------- Transpose + f32->bf16: W[K][N] -> Wt[N][K] ----------------
__global__ __launch_bounds__(256) void transpose_bf16_kernel(const float* __restrict__ W,
                                                             unsigned short* __restrict__ Wt,
                                                             int K, int N) {
  __shared__ float tile[32][33];
  const int n0 = blockIdx.x * 32, k0 = blockIdx.y * 32;
  const int tx = threadIdx.x & 31, ty = threadIdx.x >> 5;  // ty 0..7
#pragma unroll
  for (int r = 0; r < 4; r++)
    tile[ty + r * 8][tx] = W[(size_t)(k0 + ty + r * 8) * N + n0 + tx];
  __syncthreads();
#pragma unroll
  for (int r = 0; r < 4; r++)
    Wt[(size_t)(n0 + ty + r * 8) * K + k0 + tx] = f2b(tile[tx][ty + r * 8]);
}

// ---------------- 128^2 pipelined GEMM (kept for attn_proj, EP=1) ----------------
template <int EP>
__global__ __launch_bounds__(256) void gemm_kernel(const unsigned short* __restrict__ A,
                                                   const unsigned short* __restrict__ Bt,
                                                   const float* __restrict__ bias,
                                                   const float* res, void* out,
                                                   int M, int N, int K, int nx) {
  __shared__ unsigned short As[3][128 * 32];
  __shared__ unsigned short Bs[3][128 * 32];
  const int tid = threadIdx.x;
  const int lane = tid & 63, w = tid >> 6;
  const int wm = w >> 1, wn = w & 1;
  const int l15 = lane & 15, l4 = lane >> 4;

  const int nwg = gridDim.x;
  int wg = blockIdx.x;
  wg = (wg & 7) * (nwg >> 3) + (wg >> 3);
  const int tile_m = (wg / nx) * 128;
  const int tile_n = (wg % nx) * 128;

  f32x4 acc[4][4] = {};

  const int cbase0 = w * 64 + lane;
  auto stage = [&](int buf, int k0) {
#pragma unroll
    for (int i = 0; i < 2; i++) {
      const int chunk = i * 256 + cbase0;
      const int r = chunk >> 2, c = (chunk & 3) * 8;
      __builtin_amdgcn_global_load_lds(
          (gas_ptr)&A[(size_t)(tile_m + r) * K + k0 + c],
          (las_ptr)&As[buf][(i * 256 + w * 64) * 8], 16, 0, 0);
      __builtin_amdgcn_global_load_lds(
          (gas_ptr)&Bt[(size_t)(tile_n + r) * K + k0 + c],
          (las_ptr)&Bs[buf][(i * 256 + w * 64) * 8], 16, 0, 0);
    }
  };

  stage(0, 0);
  stage(1, 32);
  asm volatile("s_waitcnt vmcnt(4)" ::: "memory");
  __builtin_amdgcn_s_barrier();
  __builtin_amdgcn_sched_barrier(0);

  const int nt = K >> 5;
  for (int t = 0; t < nt; ++t) {
    if (t + 2 < nt) stage((t + 2) % 3, (t + 2) * 32);
    __builtin_amdgcn_sched_barrier(0);

    const int cur = t % 3;
    short8 a[4], b[4];
#pragma unroll
    for (int mi = 0; mi < 4; mi++)
      a[mi] = *reinterpret_cast<const short8*>(&As[cur][(wm * 64 + mi * 16 + l15) * 32 + l4 * 8]);
#pragma unroll
    for (int ni = 0; ni < 4; ni++)
      b[ni] = *reinterpret_cast<const short8*>(&Bs[cur][(wn * 64 + ni * 16 + l15) * 32 + l4 * 8]);
    asm volatile("s_waitcnt lgkmcnt(0)" ::: "memory");
    __builtin_amdgcn_sched_barrier(0);

#pragma unroll
    for (int mi = 0; mi < 4; mi++)
#pragma unroll
      for (int ni = 0; ni < 4; ni++)
        acc[mi][ni] = __builtin_amdgcn_mfma_f32_16x16x32_bf16(a[mi], b[ni], acc[mi][ni], 0, 0, 0);
    __builtin_amdgcn_sched_barrier(0);

    if (t + 2 < nt) {
      asm volatile("s_waitcnt vmcnt(4)" ::: "memory");
    } else {
      asm volatile("s_waitcnt vmcnt(0)" ::: "memory");
    }
    __builtin_amdgcn_s_barrier();
    __builtin_amdgcn_sched_barrier(0);
  }

#pragma unroll
  for (int ni = 0; ni < 4; ni++) {
    const int col = tile_n + wn * 64 + ni * 16 + l15;
    const float bv = bias[col];
#pragma unroll
    for (int mi = 0; mi < 4; mi++) {
#pragma unroll
      for (int r = 0; r < 4; r++) {
        const int row = tile_m + wm * 64 + mi * 16 + l4 * 4 + r;
        const size_t idx = (size_t)row * N + col;
        float v = acc[mi][ni][r] + bv;
        if (EP == 0) {
          ((unsigned short*)out)[idx] = f2b(v);
        } else if (EP == 1) {
          ((float*)out)[idx] = v + res[idx];
        } else {
          float g = 0.5f * v * (1.0f + erff(v * 0.70710678118f));
          ((unsigned short*)out)[idx] = f2b(g);
        }
      }
    }
  }
}

// ---------------- 256^2 8-wave deep-pipelined GEMM (m201-style) ----------------
#define BUFS 16384
template <int EP>
__global__ __launch_bounds__(512, 2) void gemm256_kernel(
    const unsigned short* __restrict__ A, const unsigned short* __restrict__ Bt,
    const float* __restrict__ bias, void* out, int M, int N, int K, int nx, int nk) {
  extern __shared__ unsigned short lds[];
  const int tid = threadIdx.x;
  const int lane = tid & 63, w = tid >> 6;
  const int wm = w >> 2, wn = w & 3;
  const int l15 = lane & 15, l4 = lane >> 4;

  const int nwg = gridDim.x;
  int wg = blockIdx.x;
  wg = (wg & 7) * (nwg >> 3) + (wg >> 3);
  const int ntile = nwg / nk;
  const int slice = wg / ntile;
  const int rem = wg % ntile;
  const int tile_m = (rem / nx) * 256;
  const int tile_n = (rem % nx) * 256;
  const int Klen = K / nk;
  const int kbase = slice * Klen;

  f32x4 acc[8][4] = {};

  auto stage = [&](int buf, int k0) {
    unsigned short* Ab = lds + buf * BUFS;
    unsigned short* Bb = Ab + 8192;
#pragma unroll
    for (int j = 0; j < 2; j++) {
      const int chunk = j * 512 + w * 64 + lane;
      const int r = chunk >> 2, c = (chunk & 3) * 8;
      __builtin_amdgcn_global_load_lds((gas_ptr)&A[(size_t)(tile_m + r) * K + k0 + c],
                                       (las_ptr)&Ab[(j * 512 + w * 64) * 8], 16, 0, 0);
      __builtin_amdgcn_global_load_lds((gas_ptr)&Bt[(size_t)(tile_n + r) * K + k0 + c],
                                       (las_ptr)&Bb[(j * 512 + w * 64) * 8], 16, 0, 0);
    }
  };

  stage(0, kbase);
  stage(1, kbase + 32);
  stage(2, kbase + 64);
  asm volatile("s_waitcnt vmcnt(8)" ::: "memory");
  __builtin_amdgcn_s_barrier();
  __builtin_amdgcn_sched_barrier(0);

  const int nt = Klen >> 5;
  for (int t = 0; t < nt; ++t) {
    if (t + 3 < nt) stage((t + 3) & 3, kbase + (t + 3) * 32);
    __builtin_amdgcn_sched_barrier(0);

    const unsigned short* Ab = lds + (t & 3) * BUFS;
    const unsigned short* Bb = Ab + 8192;
    short8 a[4], b[4];
#pragma unroll
    for (int i = 0; i < 4; i++) {
      a[i] = *reinterpret_cast<const short8*>(&Ab[(wm * 128 + i * 16 + l15) * 32 + l4 * 8]);
      b[i] = *reinterpret_cast<const short8*>(&Bb[(wn * 64 + i * 16 + l15) * 32 + l4 * 8]);
    }
    __builtin_amdgcn_s_barrier();
    asm volatile("s_waitcnt lgkmcnt(0)" ::: "memory");
    __builtin_amdgcn_sched_barrier(0);
    __builtin_amdgcn_s_setprio(1);
#pragma unroll
    for (int mi = 0; mi < 4; mi++)
#pragma unroll
      for (int ni = 0; ni < 4; ni++)
        acc[mi][ni] = __builtin_amdgcn_mfma_f32_16x16x32_bf16(a[mi], b[ni], acc[mi][ni], 0, 0, 0);
    __builtin_amdgcn_s_setprio(0);
    __builtin_amdgcn_sched_barrier(0);
    __builtin_amdgcn_s_barrier();

#pragma unroll
    for (int i = 0; i < 4; i++)
      a[i] = *reinterpret_cast<const short8*>(&Ab[(wm * 128 + 64 + i * 16 + l15) * 32 + l4 * 8]);
    asm volatile("s_waitcnt lgkmcnt(0)" ::: "memory");
    __builtin_amdgcn_sched_barrier(0);
    __builtin_amdgcn_s_setprio(1);
#pragma unroll
    for (int mi = 0; mi < 4; mi++)
#pragma unroll
      for (int ni = 0; ni < 4; ni++)
        acc[mi + 4][ni] = __builtin_amdgcn_mfma_f32_16x16x32_bf16(a[mi], b[ni], acc[mi + 4][ni], 0, 0, 0);
    __builtin_amdgcn_s_setprio(0);
    __builtin_amdgcn_sched_barrier(0);

    if (t + 3 < nt) {
      asm volatile("s_waitcnt vmcnt(8)" ::: "memory");
    } else if (t + 2 < nt) {
      asm volatile("s_waitcnt vmcnt(4)" ::: "memory");
    } else if (t + 1 < nt) {
      asm volatile("s_waitcnt vmcnt(0)" ::: "memory");
    }
    __builtin_amdgcn_s_barrier();
    __builtin_amdgcn_sched_barrier(0);
  }

#pragma unroll
  for (int ni = 0; ni < 4; ni++) {
    const int col = tile_n + wn * 64 + ni * 16 + l15;
    float bv = bias[col];
    if (EP == 3 && slice != 0) bv = 0.0f;
#pragma unroll
    for (int mi = 0; mi < 8; mi++) {
#pragma unroll
      for (int r = 0; r < 4; r++) {
        const int row = tile_m + wm * 128 + mi * 16 + l4 * 4 + r;
        const size_t idx = (size_t)row * N + col;
        float v = acc[mi][ni][r] + bv;
        if (EP == 0) {
          ((unsigned short*)out)[idx] = f2b(v);
        } else if (EP == 2) {
          float g = 0.5f * v * (1.0f + erff(v * 0.70710678118f));
          ((unsigned short*)out)[idx] = f2b(g);
        } else {
          atomicAdd(&((float*)out)[idx], v);
        }
      }
    }
  }
}

// ---------------- Strided-sparse flash attention (pair-merged, async-staged) ----------------
// 1D grid 512, 256 thr. qt remapped complementary so co-resident blocks have ~equal work.
// Per iteration: TWO 64-key tiles staged (Ks 128x64 swizzled; Vt transposed 64x[128+8]
// with xor-swizzled key index). T14: next pair's K/V global loads issued after LDS write,
// in flight across compute (second barrier is raw s_barrier + lgkmcnt(0), NO vmcnt drain;
// the loads drain at next iteration's __syncthreads, exactly where the regs are consumed).
__global__ __launch_bounds__(256) void attn_kernel(const unsigned short* __restrict__ qkv,
                                                   unsigned short* __restrict__ y) {
  const int bi = blockIdx.x;
  const int qt = (bi < 256) ? (bi & 15) : (15 - (bi & 15));
  const int bh = bi >> 4;                  // 0..31
  const int bb = bh >> 4, hh = bh & 15;
  const int q0 = qt * 128;
  const int tid = threadIdx.x;
  const int lane = tid & 63, w = tid >> 6;
  const int l15 = lane & 15, l4 = lane >> 4;

  __shared__ unsigned short Qs[128 * 64];     // 16 KB
  __shared__ unsigned short Ks[128 * 64];     // 16 KB
  __shared__ unsigned short Vt[64 * 136];     // 17 KB, Vt[d][key^swz], pad 8
  __shared__ unsigned short Ps[4][32 * 72];   // 18 KB, wave-private

  const size_t base = (size_t)bb * Tn * (3 * Cn) + hh * 64;

  // stage Q (XOR-swizzled 16B chunks within 128B rows)
#pragma unroll
  for (int i = 0; i < 4; i++) {
    const int chunk = i * 256 + tid;
    const int r = chunk >> 3, c = chunk & 7;
    uint4 v = *reinterpret_cast<const uint4*>(&qkv[base + (size_t)(q0 + r) * (3 * Cn) + c * 8]);
    *reinterpret_cast<uint4*>(&Qs[r * 64 + ((c ^ (r & 7)) * 8)]) = v;
  }
  __syncthreads();
  short8 qf[2][2];
#pragma unroll
  for (int mi = 0; mi < 2; mi++)
#pragma unroll
    for (int ks = 0; ks < 2; ks++) {
      const int r = w * 32 + mi * 16 + l15;
      const int c = ks * 4 + l4;
      qf[mi][ks] = *reinterpret_cast<const short8*>(&Qs[r * 64 + ((c ^ (r & 7)) * 8)]);
    }

  f32x4 acc_o[2][4] = {};
  float mrow[2][4], lrow[2][4];
#pragma unroll
  for (int mi = 0; mi < 2; mi++)
#pragma unroll
    for (int r = 0; r < 4; r++) { mrow[mi][r] = -1e30f; lrow[mi][r] = 0.0f; }

  const int nfar = (qt >= 1) ? (qt - 1) : 0;       // 64-key far tiles (even keys, stride 2)
  const int nstart = (q0 >= 128) ? (q0 - 128) : 0;
  const int ntiles = nfar + (q0 + 128 - nstart) / 64;
  const int np = (ntiles + 1) >> 1;

  auto tdesc = [&](int t, int& kb, int& kst) {
    if (t < nfar) { kb = t * 128; kst = 2; } else { kb = nstart + (t - nfar) * 64; kst = 1; }
  };

  uint4 kr[4], vr[4];
  auto fetch = [&](int p) {
    int kb0, ks0, kb1, ks1;
    tdesc(2 * p, kb0, ks0);
    if (2 * p + 1 < ntiles) tdesc(2 * p + 1, kb1, ks1); else { kb1 = kb0; ks1 = ks0; }
#pragma unroll
    for (int u = 0; u < 4; u++) {
      const int chunk = u * 256 + tid;             // 0..1023
      const int row = chunk >> 3, c = chunk & 7;   // row 0..127, c 0..7
      const int key = (row < 64) ? (kb0 + row * ks0) : (kb1 + (row - 64) * ks1);
      kr[u] = *reinterpret_cast<const uint4*>(&qkv[base + Cn + (size_t)key * (3 * Cn) + c * 8]);
      vr[u] = *reinterpret_cast<const uint4*>(&qkv[base + 2 * Cn + (size_t)key * (3 * Cn) + c * 8]);
    }
  };

  fetch(0);
  for (int p = 0; p < np; ++p) {
    __syncthreads();   // prev compute's LDS reads done; prefetch regs landed (vmcnt drain)

    // write staged pair to LDS
#pragma unroll
    for (int u = 0; u < 4; u++) {
      const int chunk = u * 256 + tid;
      const int row = chunk >> 3, c = chunk & 7;
      *reinterpret_cast<uint4*>(&Ks[row * 64 + ((c ^ (row & 7)) * 8)]) = kr[u];
      unsigned short tmp[8];
      *reinterpret_cast<uint4*>(tmp) = vr[u];
      const int xr = row ^ ((c & 3) << 3);
#pragma unroll
      for (int j = 0; j < 8; j++) Vt[(c * 8 + j) * 136 + xr] = tmp[j];
    }
    // T14: issue next pair's loads (stay in flight across compute)
    if (p + 1 < np) fetch(p + 1);
    __builtin_amdgcn_sched_barrier(0);
    asm volatile("s_waitcnt lgkmcnt(0)" ::: "memory");
    __builtin_amdgcn_s_barrier();
    __builtin_amdgcn_sched_barrier(0);

    // descriptors for this pair
    int kb0, ks0, kb1, ks1;
    tdesc(2 * p, kb0, ks0);
    const bool v1 = (2 * p + 1 < ntiles);
    if (v1) tdesc(2 * p + 1, kb1, ks1); else { kb1 = kb0; ks1 = ks0; }
    const bool far0 = (2 * p) < nfar;
    const bool far1 = v1 && ((2 * p + 1) < nfar);

    // S = Q K^T over 128 staged keys
    f32x4 s[2][8] = {};
#pragma unroll
    for (int ni = 0; ni < 8; ni++) {
#pragma unroll
      for (int ks = 0; ks < 2; ks++) {
        const int r = ni * 16 + l15;
        const int c = ks * 4 + l4;
        short8 kf = *reinterpret_cast<const short8*>(&Ks[r * 64 + ((c ^ (r & 7)) * 8)]);
#pragma unroll
        for (int mi = 0; mi < 2; mi++)
          s[mi][ni] = __builtin_amdgcn_mfma_f32_16x16x32_bf16(qf[mi][ks], kf, s[mi][ni], 0, 0, 0);
      }
    }

    // scale + mask
#pragma unroll
    for (int mi = 0; mi < 2; mi++)
#pragma unroll
      for (int ni = 0; ni < 8; ni++) {
        const int half = ni >> 2, nh = ni & 3;
        const int kk = half ? (kb1 + (nh * 16 + l15) * ks1) : (kb0 + (nh * 16 + l15) * ks0);
        const bool isfar = half ? far1 : far0;
        const bool gv = half ? v1 : true;
#pragma unroll
        for (int r = 0; r < 4; r++) {
          float v = s[mi][ni][r] * 0.125f;
          if (!gv) {
            v = -1e30f;
          } else if (!isfar) {
            const int iq = q0 + w * 32 + mi * 16 + l4 * 4 + r;
            const bool ok = (kk <= iq) && ((kk >= iq - 4) || ((kk & 1) == 0));
            v = ok ? v : -1e30f;
          }
          s[mi][ni][r] = v;
        }
      }

    // online softmax (one rescale per 128-key pair)
#pragma unroll
    for (int mi = 0; mi < 2; mi++)
#pragma unroll
      for (int r = 0; r < 4; r++) {
        float tm = s[mi][0][r];
#pragma unroll
        for (int ni = 1; ni < 8; ni++) tm = fmaxf(tm, s[mi][ni][r]);
        tm = fmaxf(tm, __shfl_xor(tm, 1));
        tm = fmaxf(tm, __shfl_xor(tm, 2));
        tm = fmaxf(tm, __shfl_xor(tm, 4));
        tm = fmaxf(tm, __shfl_xor(tm, 8));
        const float mnew = fmaxf(mrow[mi][r], tm);
        const float alpha = __expf(mrow[mi][r] - mnew);
        mrow[mi][r] = mnew;
        lrow[mi][r] *= alpha;
#pragma unroll
        for (int nd = 0; nd < 4; nd++) acc_o[mi][nd][r] *= alpha;
        float rs = 0.0f;
#pragma unroll
        for (int ni = 0; ni < 8; ni++) {
          const float pv = __expf(s[mi][ni][r] - mnew);
          s[mi][ni][r] = pv;
          rs += pv;
        }
        rs += __shfl_xor(rs, 1); rs += __shfl_xor(rs, 2);
        rs += __shfl_xor(rs, 4); rs += __shfl_xor(rs, 8);
        lrow[mi][r] += rs;
      }

    // O += P @ V  in two 64-key halves (Ps wave-private roundtrip reused)
#pragma unroll
    for (int h = 0; h < 2; h++) {
#pragma unroll
      for (int mi = 0; mi < 2; mi++)
#pragma unroll
        for (int n4 = 0; n4 < 4; n4++)
#pragma unroll
          for (int r = 0; r < 4; r++)
            Ps[w][(mi * 16 + l4 * 4 + r) * 72 + n4 * 16 + l15] = f2b(s[mi][h * 4 + n4][r]);

#pragma unroll
      for (int kss = 0; kss < 2; kss++) {
        short8 pf[2];
#pragma unroll
        for (int mi = 0; mi < 2; mi++)
          pf[mi] = *reinterpret_cast<const short8*>(&Ps[w][(mi * 16 + l15) * 72 + kss * 32 + l4 * 8]);
#pragma unroll
        for (int nd = 0; nd < 4; nd++) {
          const int d = nd * 16 + l15;
          const int kcol = ((h * 2 + kss) * 32 + l4 * 8) ^ (((d >> 3) & 3) << 3);
          short8 vf = *reinterpret_cast<const short8*>(&Vt[d * 136 + kcol]);
#pragma unroll
          for (int mi = 0; mi < 2; mi++)
            acc_o[mi][nd] = __builtin_amdgcn_mfma_f32_16x16x32_bf16(pf[mi], vf, acc_o[mi][nd], 0, 0, 0);
        }
      }
    }
  }

  // normalize + write y
#pragma unroll
  for (int mi = 0; mi < 2; mi++)
#pragma unroll
    for (int r = 0; r < 4; r++) {
      const float inv = 1.0f / lrow[mi][r];
      const int row = q0 + w * 32 + mi * 16 + l4 * 4 + r;
#pragma unroll
      for (int nd = 0; nd < 4; nd++) {
        const int col = nd * 16 + l15;
        y[((size_t)bb * Tn + row) * Cn + hh * 64 + col] = f2b(acc_o[mi][nd][r] * inv);
      }
    }
}

// ---------------- launch ----------------
extern "C" void kernel_launch(void* const* d_in, const int* in_sizes, int n_in,
                              void* d_out, int out_size, void* d_ws, size_t ws_size,
                              hipStream_t stream) {
  const float* x           = (const float*)d_in[0];
  const float* ln1_w       = (const float*)d_in[1];
  const float* ln1_b       = (const float*)d_in[2];
  const float* c_attn_w    = (const float*)d_in[3];
  const float* c_attn_b    = (const float*)d_in[4];
  const float* attn_proj_w = (const float*)d_in[5];
  const float* attn_proj_b = (const float*)d_in[6];
  const float* ln2_w       = (const float*)d_in[7];
  const float* ln2_b       = (const float*)d_in[8];
  const float* fc_w        = (const float*)d_in[9];
  const float* fc_b        = (const float*)d_in[10];
  const float* mlp_proj_w  = (const float*)d_in[11];
  const float* mlp_proj_b  = (const float*)d_in[12];
  float* out = (float*)d_out;

  char* ws = (char*)d_ws;
  unsigned short* wT1 = (unsigned short*)(ws);                     // [3072][1024]
  unsigned short* wT2 = (unsigned short*)(ws + 6291456);           // [1024][1024]
  unsigned short* wT3 = (unsigned short*)(ws + 8388608);           // [4096][1024]
  unsigned short* wT4 = (unsigned short*)(ws + 16777216);          // [1024][4096]
  unsigned short* h   = (unsigned short*)(ws + 25165824);          // [4096][1024]
  unsigned short* qkv = (unsigned short*)(ws + 33554432);          // [4096][3072] / [4096][4096]
  unsigned short* yb  = (unsigned short*)(ws + 67108864);          // [4096][1024]

  hipFuncSetAttribute((const void*)gemm256_kernel<0>, hipFuncAttributeMaxDynamicSharedMemorySize, 131072);
  hipFuncSetAttribute((const void*)gemm256_kernel<2>, hipFuncAttributeMaxDynamicSharedMemorySize, 131072);
  hipFuncSetAttribute((const void*)gemm256_kernel<3>, hipFuncAttributeMaxDynamicSharedMemorySize, 131072);

  transpose_bf16_kernel<<<dim3(3072 / 32, 1024 / 32), 256, 0, stream>>>(c_attn_w, wT1, 1024, 3072);
  transpose_bf16_kernel<<<dim3(1024 / 32, 1024 / 32), 256, 0, stream>>>(attn_proj_w, wT2, 1024, 1024);
  transpose_bf16_kernel<<<dim3(4096 / 32, 1024 / 32), 256, 0, stream>>>(fc_w, wT3, 1024, 4096);
  transpose_bf16_kernel<<<dim3(1024 / 32, 4096 / 32), 256, 0, stream>>>(mlp_proj_w, wT4, 4096, 1024);

  ln_kernel<<<Mrows, 256, 0, stream>>>(x, ln1_w, ln1_b, h);
  gemm256_kernel<0><<<(Mrows / 256) * (3072 / 256), 512, 131072, stream>>>(
      h, wT1, c_attn_b, qkv, Mrows, 3072, 1024, 3072 / 256, 1);
  attn_kernel<<<512, 256, 0, stream>>>(qkv, yb);
  gemm_kernel<1><<<(1024 / 128) * (Mrows / 128), 256, 0, stream>>>(yb, wT2, attn_proj_b, x, out, Mrows, 1024, 1024, 1024 / 128);
  ln_kernel<<<Mrows, 256, 0, stream>>>(out, ln2_w, ln2_b, h);
  gemm256_kernel<2><<<(Mrows / 256) * (4096 / 256), 512, 131072, stream>>>(
      h, wT3, fc_b, qkv, Mrows, 4096, 1024, 4096 / 256, 1);
  gemm256_kernel<3><<<(Mrows / 256) * (1024 / 256) * 4, 512, 131072, stream>>>(
      qkv, wT4, mlp_proj_b, out, Mrows, 1024, 4096, 1024 / 256, 4);
}

// Round 8
// 326.139 us; speedup vs baseline: 1.0796x; 1.0796x over previous
//
#include <hip/hip_runtime.h>
#include <hip/hip_bf16.h>

#define Bn 2
#define Tn 2048
#define Cn 1024
#define Hn 16
#define Dn 64
#define Mrows (Bn * Tn)   // 4096

typedef __attribute__((ext_vector_type(8))) short short8;
typedef __attribute__((ext_vector_type(4))) float f32x4;

typedef const __attribute__((address_space(1))) unsigned int* gas_ptr;
typedef __attribute__((address_space(3))) unsigned int* las_ptr;

__device__ __forceinline__ unsigned short f2b(float f) {
  unsigned int u = __builtin_bit_cast(unsigned int, f);
  return (unsigned short)((u + 0x7fffu + ((u >> 16) & 1u)) >> 16);
}

// ---------------- LayerNorm: f32 in -> bf16 out ----------------
__global__ __launch_bounds__(256) void ln_kernel(const float* __restrict__ x,
                                                 const float* __restrict__ w,
                                                 const float* __restrict__ b,
                                                 unsigned short* __restrict__ out) {
  const int row = blockIdx.x;
  const int t = threadIdx.x;
  const float4 v = *reinterpret_cast<const float4*>(x + (size_t)row * Cn + t * 4);
  float s = v.x + v.y + v.z + v.w;
  float s2 = v.x * v.x + v.y * v.y + v.z * v.z + v.w * v.w;
#pragma unroll
  for (int m = 1; m < 64; m <<= 1) { s += __shfl_xor(s, m); s2 += __shfl_xor(s2, m); }
  __shared__ float ls[4], ls2[4];
  if ((t & 63) == 0) { ls[t >> 6] = s; ls2[t >> 6] = s2; }
  __syncthreads();
  s  = ls[0] + ls[1] + ls[2] + ls[3];
  s2 = ls2[0] + ls2[1] + ls2[2] + ls2[3];
  const float mu = s * (1.0f / Cn);
  const float rstd = rsqrtf(s2 * (1.0f / Cn) - mu * mu + 1e-5f);
  const float4 wv = *reinterpret_cast<const float4*>(w + t * 4);
  const float4 bv = *reinterpret_cast<const float4*>(b + t * 4);
  unsigned short o[4];
  o[0] = f2b((v.x - mu) * rstd * wv.x + bv.x);
  o[1] = f2b((v.y - mu) * rstd * wv.y + bv.y);
  o[2] = f2b((v.z - mu) * rstd * wv.z + bv.z);
  o[3] = f2b((v.w - mu) * rstd * wv.w + bv.w);
  *reinterpret_cast<uint2*>(out + (size_t)row * Cn + t * 4) = *reinterpret_cast<uint2*>(o);
}

// ---------------- Transpose + f32->bf16: W[K][N] -> Wt[N][K] ----------------
__global__ __launch_bounds__(256) void transpose_bf16_kernel(const float* __restrict__ W,
                                                             unsigned short* __restrict__ Wt,
                                                             int K, int N) {
  __shared__ float tile[32][33];
  const int n0 = blockIdx.x * 32, k0 = blockIdx.y * 32;
  const int tx = threadIdx.x & 31, ty = threadIdx.x >> 5;  // ty 0..7
#pragma unroll
  for (int r = 0; r < 4; r++)
    tile[ty + r * 8][tx] = W[(size_t)(k0 + ty + r * 8) * N + n0 + tx];
  __syncthreads();
#pragma unroll
  for (int r = 0; r < 4; r++)
    Wt[(size_t)(n0 + ty + r * 8) * K + k0 + tx] = f2b(tile[tx][ty + r * 8]);
}

// ---------------- 256^2 8-wave deep-pipelined GEMM (m201-style) ----------------
// EP=0: bf16 = v+bias; EP=2: bf16 = gelu(v+bias); EP=3: f32 atomicAdd(out, v [+bias if slice0])
#define BUFS 16384
template <int EP>
__global__ __launch_bounds__(512, 2) void gemm256_kernel(
    const unsigned short* __restrict__ A, const unsigned short* __restrict__ Bt,
    const float* __restrict__ bias, void* out, int M, int N, int K, int nx, int nk) {
  extern __shared__ unsigned short lds[];
  const int tid = threadIdx.x;
  const int lane = tid & 63, w = tid >> 6;
  const int wm = w >> 2, wn = w & 3;
  const int l15 = lane & 15, l4 = lane >> 4;

  const int nwg = gridDim.x;
  int wg = blockIdx.x;
  wg = (wg & 7) * (nwg >> 3) + (wg >> 3);
  const int ntile = nwg / nk;
  const int slice = wg / ntile;
  const int rem = wg % ntile;
  const int tile_m = (rem / nx) * 256;
  const int tile_n = (rem % nx) * 256;
  const int Klen = K / nk;
  const int kbase = slice * Klen;

  f32x4 acc[8][4] = {};

  auto stage = [&](int buf, int k0) {
    unsigned short* Ab = lds + buf * BUFS;
    unsigned short* Bb = Ab + 8192;
#pragma unroll
    for (int j = 0; j < 2; j++) {
      const int chunk = j * 512 + w * 64 + lane;
      const int r = chunk >> 2, c = (chunk & 3) * 8;
      __builtin_amdgcn_global_load_lds((gas_ptr)&A[(size_t)(tile_m + r) * K + k0 + c],
                                       (las_ptr)&Ab[(j * 512 + w * 64) * 8], 16, 0, 0);
      __builtin_amdgcn_global_load_lds((gas_ptr)&Bt[(size_t)(tile_n + r) * K + k0 + c],
                                       (las_ptr)&Bb[(j * 512 + w * 64) * 8], 16, 0, 0);
    }
  };

  stage(0, kbase);
  stage(1, kbase + 32);
  stage(2, kbase + 64);
  asm volatile("s_waitcnt vmcnt(8)" ::: "memory");
  __builtin_amdgcn_s_barrier();
  __builtin_amdgcn_sched_barrier(0);

  const int nt = Klen >> 5;
  for (int t = 0; t < nt; ++t) {
    if (t + 3 < nt) stage((t + 3) & 3, kbase + (t + 3) * 32);
    __builtin_amdgcn_sched_barrier(0);

    const unsigned short* Ab = lds + (t & 3) * BUFS;
    const unsigned short* Bb = Ab + 8192;
    short8 a[4], b[4];
#pragma unroll
    for (int i = 0; i < 4; i++) {
      a[i] = *reinterpret_cast<const short8*>(&Ab[(wm * 128 + i * 16 + l15) * 32 + l4 * 8]);
      b[i] = *reinterpret_cast<const short8*>(&Bb[(wn * 64 + i * 16 + l15) * 32 + l4 * 8]);
    }
    __builtin_amdgcn_s_barrier();
    asm volatile("s_waitcnt lgkmcnt(0)" ::: "memory");
    __builtin_amdgcn_sched_barrier(0);
    __builtin_amdgcn_s_setprio(1);
#pragma unroll
    for (int mi = 0; mi < 4; mi++)
#pragma unroll
      for (int ni = 0; ni < 4; ni++)
        acc[mi][ni] = __builtin_amdgcn_mfma_f32_16x16x32_bf16(a[mi], b[ni], acc[mi][ni], 0, 0, 0);
    __builtin_amdgcn_s_setprio(0);
    __builtin_amdgcn_sched_barrier(0);
    __builtin_amdgcn_s_barrier();

#pragma unroll
    for (int i = 0; i < 4; i++)
      a[i] = *reinterpret_cast<const short8*>(&Ab[(wm * 128 + 64 + i * 16 + l15) * 32 + l4 * 8]);
    asm volatile("s_waitcnt lgkmcnt(0)" ::: "memory");
    __builtin_amdgcn_sched_barrier(0);
    __builtin_amdgcn_s_setprio(1);
#pragma unroll
    for (int mi = 0; mi < 4; mi++)
#pragma unroll
      for (int ni = 0; ni < 4; ni++)
        acc[mi + 4][ni] = __builtin_amdgcn_mfma_f32_16x16x32_bf16(a[mi], b[ni], acc[mi + 4][ni], 0, 0, 0);
    __builtin_amdgcn_s_setprio(0);
    __builtin_amdgcn_sched_barrier(0);

    if (t + 3 < nt) {
      asm volatile("s_waitcnt vmcnt(8)" ::: "memory");
    } else if (t + 2 < nt) {
      asm volatile("s_waitcnt vmcnt(4)" ::: "memory");
    } else if (t + 1 < nt) {
      asm volatile("s_waitcnt vmcnt(0)" ::: "memory");
    }
    __builtin_amdgcn_s_barrier();
    __builtin_amdgcn_sched_barrier(0);
  }

#pragma unroll
  for (int ni = 0; ni < 4; ni++) {
    const int col = tile_n + wn * 64 + ni * 16 + l15;
    float bv = bias[col];
    if (EP == 3 && slice != 0) bv = 0.0f;
#pragma unroll
    for (int mi = 0; mi < 8; mi++) {
#pragma unroll
      for (int r = 0; r < 4; r++) {
        const int row = tile_m + wm * 128 + mi * 16 + l4 * 4 + r;
        const size_t idx = (size_t)row * N + col;
        float v = acc[mi][ni][r] + bv;
        if (EP == 0) {
          ((unsigned short*)out)[idx] = f2b(v);
        } else if (EP == 2) {
          float g = 0.5f * v * (1.0f + erff(v * 0.70710678118f));
          ((unsigned short*)out)[idx] = f2b(g);
        } else {
          atomicAdd(&((float*)out)[idx], v);
        }
      }
    }
  }
}

// ---------------- Strided-sparse flash attention v3 ----------------
// QBLK=64, grid 1024 (4 blocks/CU), 256 thr / 4 waves, each wave 16 q-rows.
// LDS 34 KB: Kbuf[2] (Qs overlays Kbuf0, prologue-only) + Vt + Ps.
// K staged via global_load_lds with PRE-SWIZZLED global source (linear LDS dest);
// V reg-fetched, transpose-written with full row^(c<<3) swizzle (write: 32 banks).
// T14: K(t+1)/V(t+1) issued before the mid-barrier; mid-barrier is s_barrier +
// lgkmcnt(0) ONLY (no vmcnt drain) so they fly across compute and drain at the
// end-__syncthreads, exactly where they're consumed next iteration.
// Complementary qt remap: each CU's 4 resident blocks get qt from the 4 quarters
// {sub, 15-sub, 16+sub, 31-sub} -> constant total work per CU.
__global__ __launch_bounds__(256, 4) void attn_kernel(const unsigned short* __restrict__ qkv,
                                                      unsigned short* __restrict__ y) {
  __shared__ unsigned short SH[17408];   // 34816 B
  const int tid = threadIdx.x;
  const int lane = tid & 63, w = tid >> 6;
  const int l15 = lane & 15, l4 = lane >> 4;

  const int bi = blockIdx.x;
  const int quarter = bi >> 8, rest = bi & 255;
  const int bh = rest >> 3, sub = rest & 7;
  int qt;
  if (quarter == 0) qt = sub;
  else if (quarter == 1) qt = 15 - sub;
  else if (quarter == 2) qt = 16 + sub;
  else qt = 31 - sub;
  const int bb = bh >> 4, hh = bh & 15;
  const int q0 = qt * 64;
  const size_t base = (size_t)bb * Tn * (3 * Cn) + hh * 64;

  const int nfar = qt >> 1;                    // far tiles: 64 even keys each
  const int ntiles = nfar + (q0 ? 2 : 1);

  unsigned short* Vt = SH + 8192;              // [64 d][72], swizzled key index
  unsigned short* Ps = SH + 12800 + w * 1152;  // per-wave [16][72]

  auto keyof = [&](int t, int row) -> int {
    if (t < nfar) return t * 128 + 2 * row;    // gathered even keys
    return q0 - 64 * (ntiles - 1 - t) + row;   // near tiles, ascending
  };
  auto stageK = [&](int t) {
    unsigned short* kb = SH + ((t & 1) << 12);
#pragma unroll
    for (int u = 0; u < 2; u++) {
      const int chunk = u * 256 + tid;
      const int row = chunk >> 3, cc = chunk & 7;
      const int csrc = cc ^ (row & 7);         // pre-swizzled source, linear dest
      const int key = keyof(t, row);
      __builtin_amdgcn_global_load_lds(
          (gas_ptr)&qkv[base + Cn + (size_t)key * (3 * Cn) + csrc * 8],
          (las_ptr)&kb[(u * 256 + (w << 6)) * 8], 16, 0, 0);
    }
  };
  uint4 vr[2];
  auto fetchV = [&](int t) {
#pragma unroll
    for (int u = 0; u < 2; u++) {
      const int chunk = u * 256 + tid;
      const int row = chunk >> 3, cc = chunk & 7;
      const int key = keyof(t, row);
      vr[u] = *reinterpret_cast<const uint4*>(&qkv[base + 2 * Cn + (size_t)key * (3 * Cn) + cc * 8]);
    }
  };

  // ---- prologue: Q -> SH[0,4096) (pre-swizzled gload), hoist, then reuse as Kbuf0
#pragma unroll
  for (int u = 0; u < 2; u++) {
    const int chunk = u * 256 + tid;
    const int row = chunk >> 3, cc = chunk & 7;
    const int csrc = cc ^ (row & 7);
    __builtin_amdgcn_global_load_lds(
        (gas_ptr)&qkv[base + (size_t)(q0 + row) * (3 * Cn) + csrc * 8],
        (las_ptr)&SH[(u * 256 + (w << 6)) * 8], 16, 0, 0);
  }
  __syncthreads();
  short8 qf[2];
#pragma unroll
  for (int ks = 0; ks < 2; ks++) {
    const int r = (w << 4) + l15;
    qf[ks] = *reinterpret_cast<const short8*>(&SH[r * 64 + (((ks * 4 + l4) ^ (l15 & 7)) * 8)]);
  }
  asm volatile("s_waitcnt lgkmcnt(0)" ::: "memory");   // all waves done reading Qs
  __builtin_amdgcn_s_barrier();
  __builtin_amdgcn_sched_barrier(0);
  stageK(0);
  fetchV(0);
  __syncthreads();                                     // K0 + vr0 landed

  f32x4 acc_o[4] = {};
  float mrow[4], lrow[4];
#pragma unroll
  for (int r = 0; r < 4; r++) { mrow[r] = -1e30f; lrow[r] = 0.0f; }

  for (int t = 0; t < ntiles; ++t) {
    // 1. write V(t) (swizzled transpose; write pattern covers all 32 banks)
#pragma unroll
    for (int u = 0; u < 2; u++) {
      const int chunk = u * 256 + tid;
      const int row = chunk >> 3, cc = chunk & 7;
      unsigned short tmp[8];
      *reinterpret_cast<uint4*>(tmp) = vr[u];
      const int xr = row ^ (cc << 3);
#pragma unroll
      for (int j = 0; j < 8; j++) Vt[(cc * 8 + j) * 72 + xr] = tmp[j];
    }
    // 2. prefetch t+1 (stays in flight across compute — drains at end-sync)
    if (t + 1 < ntiles) { stageK(t + 1); fetchV(t + 1); }
    // 3. mid barrier: V visible; NO vmcnt drain
    asm volatile("s_waitcnt lgkmcnt(0)" ::: "memory");
    __builtin_amdgcn_s_barrier();
    __builtin_amdgcn_sched_barrier(0);

    // 4. compute
    const unsigned short* Kb = SH + ((t & 1) << 12);
    f32x4 s[4] = {};
#pragma unroll
    for (int ni = 0; ni < 4; ni++) {
#pragma unroll
      for (int ks = 0; ks < 2; ks++) {
        const int r = ni * 16 + l15;
        short8 kf = *reinterpret_cast<const short8*>(&Kb[r * 64 + (((ks * 4 + l4) ^ (l15 & 7)) * 8)]);
        s[ni] = __builtin_amdgcn_mfma_f32_16x16x32_bf16(qf[ks], kf, s[ni], 0, 0, 0);
      }
    }

    const bool far = (t < nfar);
    const int kb0 = far ? t * 128 : q0 - 64 * (ntiles - 1 - t);
#pragma unroll
    for (int ni = 0; ni < 4; ni++) {
      const int pos = ni * 16 + l15;
      const int j = far ? kb0 + 2 * pos : kb0 + pos;
#pragma unroll
      for (int r = 0; r < 4; r++) {
        float v = s[ni][r] * 0.125f;
        if (far) {
          v = (j < q0 - 64) ? v : -1e30f;
        } else {
          const int iq = q0 + (w << 4) + l4 * 4 + r;
          const bool ok = (j <= iq) && ((j >= iq - 4) || ((j & 1) == 0));
          v = ok ? v : -1e30f;
        }
        s[ni][r] = v;
      }
    }

    // online softmax
#pragma unroll
    for (int r = 0; r < 4; r++) {
      float tm = fmaxf(fmaxf(s[0][r], s[1][r]), fmaxf(s[2][r], s[3][r]));
      tm = fmaxf(tm, __shfl_xor(tm, 1));
      tm = fmaxf(tm, __shfl_xor(tm, 2));
      tm = fmaxf(tm, __shfl_xor(tm, 4));
      tm = fmaxf(tm, __shfl_xor(tm, 8));
      const float mnew = fmaxf(mrow[r], tm);
      const float alpha = __expf(mrow[r] - mnew);
      mrow[r] = mnew;
      lrow[r] *= alpha;
#pragma unroll
      for (int nd = 0; nd < 4; nd++) acc_o[nd][r] *= alpha;
      float rs = 0.0f;
#pragma unroll
      for (int ni = 0; ni < 4; ni++) {
        const float pv = __expf(s[ni][r] - mnew);
        s[ni][r] = pv;
        rs += pv;
      }
      rs += __shfl_xor(rs, 1); rs += __shfl_xor(rs, 2);
      rs += __shfl_xor(rs, 4); rs += __shfl_xor(rs, 8);
      lrow[r] += rs;
    }

    // P -> LDS (C-layout to A-layout), wave-private
#pragma unroll
    for (int ni = 0; ni < 4; ni++)
#pragma unroll
      for (int r = 0; r < 4; r++)
        Ps[(l4 * 4 + r) * 72 + ni * 16 + l15] = f2b(s[ni][r]);

    // O += P @ V
#pragma unroll
    for (int kss = 0; kss < 2; kss++) {
      short8 pf = *reinterpret_cast<const short8*>(&Ps[l15 * 72 + kss * 32 + l4 * 8]);
#pragma unroll
      for (int nd = 0; nd < 4; nd++) {
        const int d = nd * 16 + l15;
        const int kcol = (kss * 32 + l4 * 8) ^ ((d >> 3) << 3);
        short8 vf = *reinterpret_cast<const short8*>(&Vt[d * 72 + kcol]);
        acc_o[nd] = __builtin_amdgcn_mfma_f32_16x16x32_bf16(pf, vf, acc_o[nd], 0, 0, 0);
      }
    }

    // 5. end barrier: LDS reads done for reuse; vmcnt drained -> K(t+1)/vr(t+1) ready
    __syncthreads();
  }

  // normalize + write y
#pragma unroll
  for (int r = 0; r < 4; r++) {
    const float inv = 1.0f / lrow[r];
    const int row = q0 + (w << 4) + l4 * 4 + r;
#pragma unroll
    for (int nd = 0; nd < 4; nd++) {
      const int col = nd * 16 + l15;
      y[((size_t)bb * Tn + row) * Cn + hh * 64 + col] = f2b(acc_o[nd][r] * inv);
    }
  }
}

// ---------------- launch ----------------
extern "C" void kernel_launch(void* const* d_in, const int* in_sizes, int n_in,
                              void* d_out, int out_size, void* d_ws, size_t ws_size,
                              hipStream_t stream) {
  const float* x           = (const float*)d_in[0];
  const float* ln1_w       = (const float*)d_in[1];
  const float* ln1_b       = (const float*)d_in[2];
  const float* c_attn_w    = (const float*)d_in[3];
  const float* c_attn_b    = (const float*)d_in[4];
  const float* attn_proj_w = (const float*)d_in[5];
  const float* attn_proj_b = (const float*)d_in[6];
  const float* ln2_w       = (const float*)d_in[7];
  const float* ln2_b       = (const float*)d_in[8];
  const float* fc_w        = (const float*)d_in[9];
  const float* fc_b        = (const float*)d_in[10];
  const float* mlp_proj_w  = (const float*)d_in[11];
  const float* mlp_proj_b  = (const float*)d_in[12];
  float* out = (float*)d_out;

  char* ws = (char*)d_ws;
  unsigned short* wT1 = (unsigned short*)(ws);                     // [3072][1024]
  unsigned short* wT2 = (unsigned short*)(ws + 6291456);           // [1024][1024]
  unsigned short* wT3 = (unsigned short*)(ws + 8388608);           // [4096][1024]
  unsigned short* wT4 = (unsigned short*)(ws + 16777216);          // [1024][4096]
  unsigned short* h   = (unsigned short*)(ws + 25165824);          // [4096][1024]
  unsigned short* qkv = (unsigned short*)(ws + 33554432);          // [4096][3072] / [4096][4096]
  unsigned short* yb  = (unsigned short*)(ws + 67108864);          // [4096][1024]

  hipFuncSetAttribute((const void*)gemm256_kernel<0>, hipFuncAttributeMaxDynamicSharedMemorySize, 131072);
  hipFuncSetAttribute((const void*)gemm256_kernel<2>, hipFuncAttributeMaxDynamicSharedMemorySize, 131072);
  hipFuncSetAttribute((const void*)gemm256_kernel<3>, hipFuncAttributeMaxDynamicSharedMemorySize, 131072);

  transpose_bf16_kernel<<<dim3(3072 / 32, 1024 / 32), 256, 0, stream>>>(c_attn_w, wT1, 1024, 3072);
  transpose_bf16_kernel<<<dim3(1024 / 32, 1024 / 32), 256, 0, stream>>>(attn_proj_w, wT2, 1024, 1024);
  transpose_bf16_kernel<<<dim3(4096 / 32, 1024 / 32), 256, 0, stream>>>(fc_w, wT3, 1024, 4096);
  transpose_bf16_kernel<<<dim3(1024 / 32, 4096 / 32), 256, 0, stream>>>(mlp_proj_w, wT4, 4096, 1024);

  // LN1
  ln_kernel<<<Mrows, 256, 0, stream>>>(x, ln1_w, ln1_b, h);
  // qkv = h @ c_attn_w + b   [4096, 3072]
  gemm256_kernel<0><<<(Mrows / 256) * (3072 / 256), 512, 131072, stream>>>(
      h, wT1, c_attn_b, qkv, Mrows, 3072, 1024, 3072 / 256, 1);
  // attention -> y  (1024 blocks, complementary qt balance)
  attn_kernel<<<1024, 256, 0, stream>>>(qkv, yb);
  // x1 = x + y @ attn_proj_w + b : memcpy residual, then split-K atomic GEMM
  hipMemcpyAsync(out, x, (size_t)Mrows * Cn * sizeof(float), hipMemcpyDeviceToDevice, stream);
  gemm256_kernel<3><<<(Mrows / 256) * (1024 / 256) * 4, 512, 131072, stream>>>(
      yb, wT2, attn_proj_b, out, Mrows, 1024, 1024, 1024 / 256, 4);
  // LN2 on x1
  ln_kernel<<<Mrows, 256, 0, stream>>>(out, ln2_w, ln2_b, h);
  // a = gelu(h2 @ fc_w + b)   [4096, 4096]
  gemm256_kernel<2><<<(Mrows / 256) * (4096 / 256), 512, 131072, stream>>>(
      h, wT3, fc_b, qkv, Mrows, 4096, 1024, 4096 / 256, 1);
  // out += a @ mlp_proj_w + b   split-K=4, atomicAdd epilogue
  gemm256_kernel<3><<<(Mrows / 256) * (1024 / 256) * 4, 512, 131072, stream>>>(
      qkv, wT4, mlp_proj_b, out, Mrows, 1024, 4096, 1024 / 256, 4);
}

// Round 9
// 256.248 us; speedup vs baseline: 1.3740x; 1.2727x over previous
//
#include <hip/hip_runtime.h>
#include <hip/hip_bf16.h>

#define Bn 2
#define Tn 2048
#define Cn 1024
#define Hn 16
#define Dn 64
#define Mrows (Bn * Tn)   // 4096

typedef __attribute__((ext_vector_type(8))) short short8;
typedef __attribute__((ext_vector_type(4))) float f32x4;

typedef const __attribute__((address_space(1))) unsigned int* gas_ptr;
typedef __attribute__((address_space(3))) unsigned int* las_ptr;

__device__ __forceinline__ unsigned short f2b(float f) {
  unsigned int u = __builtin_bit_cast(unsigned int, f);
  return (unsigned short)((u + 0x7fffu + ((u >> 16) & 1u)) >> 16);
}

// ---------------- LayerNorm: f32 in -> bf16 out ----------------
__global__ __launch_bounds__(256) void ln_kernel(const float* __restrict__ x,
                                                 const float* __restrict__ w,
                                                 const float* __restrict__ b,
                                                 unsigned short* __restrict__ out) {
  const int row = blockIdx.x;
  const int t = threadIdx.x;
  const float4 v = *reinterpret_cast<const float4*>(x + (size_t)row * Cn + t * 4);
  float s = v.x + v.y + v.z + v.w;
  float s2 = v.x * v.x + v.y * v.y + v.z * v.z + v.w * v.w;
#pragma unroll
  for (int m = 1; m < 64; m <<= 1) { s += __shfl_xor(s, m); s2 += __shfl_xor(s2, m); }
  __shared__ float ls[4], ls2[4];
  if ((t & 63) == 0) { ls[t >> 6] = s; ls2[t >> 6] = s2; }
  __syncthreads();
  s  = ls[0] + ls[1] + ls[2] + ls[3];
  s2 = ls2[0] + ls2[1] + ls2[2] + ls2[3];
  const float mu = s * (1.0f / Cn);
  const float rstd = rsqrtf(s2 * (1.0f / Cn) - mu * mu + 1e-5f);
  const float4 wv = *reinterpret_cast<const float4*>(w + t * 4);
  const float4 bv = *reinterpret_cast<const float4*>(b + t * 4);
  unsigned short o[4];
  o[0] = f2b((v.x - mu) * rstd * wv.x + bv.x);
  o[1] = f2b((v.y - mu) * rstd * wv.y + bv.y);
  o[2] = f2b((v.z - mu) * rstd * wv.z + bv.z);
  o[3] = f2b((v.w - mu) * rstd * wv.w + bv.w);
  *reinterpret_cast<uint2*>(out + (size_t)row * Cn + t * 4) = *reinterpret_cast<uint2*>(o);
}

// ---------------- Transpose + f32->bf16: W[K][N] -> Wt[N][K] ----------------
__global__ __launch_bounds__(256) void transpose_bf16_kernel(const float* __restrict__ W,
                                                             unsigned short* __restrict__ Wt,
                                                             int K, int N) {
  __shared__ float tile[32][33];
  const int n0 = blockIdx.x * 32, k0 = blockIdx.y * 32;
  const int tx = threadIdx.x & 31, ty = threadIdx.x >> 5;  // ty 0..7
#pragma unroll
  for (int r = 0; r < 4; r++)
    tile[ty + r * 8][tx] = W[(size_t)(k0 + ty + r * 8) * N + n0 + tx];
  __syncthreads();
#pragma unroll
  for (int r = 0; r < 4; r++)
    Wt[(size_t)(n0 + ty + r * 8) * K + k0 + tx] = f2b(tile[tx][ty + r * 8]);
}

// ---------------- 256^2 8-wave deep-pipelined GEMM (m201-style) ----------------
// EP=0: bf16 = v+bias; EP=2: bf16 = gelu(v+bias)
#define BUFS 16384
template <int EP>
__global__ __launch_bounds__(512, 2) void gemm256_kernel(
    const unsigned short* __restrict__ A, const unsigned short* __restrict__ Bt,
    const float* __restrict__ bias, void* out, int M, int N, int K, int nx) {
  extern __shared__ unsigned short lds[];
  const int tid = threadIdx.x;
  const int lane = tid & 63, w = tid >> 6;
  const int wm = w >> 2, wn = w & 3;
  const int l15 = lane & 15, l4 = lane >> 4;

  const int nwg = gridDim.x;
  int wg = blockIdx.x;
  wg = (wg & 7) * (nwg >> 3) + (wg >> 3);
  const int tile_m = (wg / nx) * 256;
  const int tile_n = (wg % nx) * 256;

  f32x4 acc[8][4] = {};

  auto stage = [&](int buf, int k0) {
    unsigned short* Ab = lds + buf * BUFS;
    unsigned short* Bb = Ab + 8192;
#pragma unroll
    for (int j = 0; j < 2; j++) {
      const int chunk = j * 512 + w * 64 + lane;
      const int r = chunk >> 2, c = (chunk & 3) * 8;
      __builtin_amdgcn_global_load_lds((gas_ptr)&A[(size_t)(tile_m + r) * K + k0 + c],
                                       (las_ptr)&Ab[(j * 512 + w * 64) * 8], 16, 0, 0);
      __builtin_amdgcn_global_load_lds((gas_ptr)&Bt[(size_t)(tile_n + r) * K + k0 + c],
                                       (las_ptr)&Bb[(j * 512 + w * 64) * 8], 16, 0, 0);
    }
  };

  stage(0, 0);
  stage(1, 32);
  stage(2, 64);
  asm volatile("s_waitcnt vmcnt(8)" ::: "memory");
  __builtin_amdgcn_s_barrier();
  __builtin_amdgcn_sched_barrier(0);

  const int nt = K >> 5;
  for (int t = 0; t < nt; ++t) {
    if (t + 3 < nt) stage((t + 3) & 3, (t + 3) * 32);
    __builtin_amdgcn_sched_barrier(0);

    const unsigned short* Ab = lds + (t & 3) * BUFS;
    const unsigned short* Bb = Ab + 8192;
    short8 a[4], b[4];
#pragma unroll
    for (int i = 0; i < 4; i++) {
      a[i] = *reinterpret_cast<const short8*>(&Ab[(wm * 128 + i * 16 + l15) * 32 + l4 * 8]);
      b[i] = *reinterpret_cast<const short8*>(&Bb[(wn * 64 + i * 16 + l15) * 32 + l4 * 8]);
    }
    __builtin_amdgcn_s_barrier();
    asm volatile("s_waitcnt lgkmcnt(0)" ::: "memory");
    __builtin_amdgcn_sched_barrier(0);
    __builtin_amdgcn_s_setprio(1);
#pragma unroll
    for (int mi = 0; mi < 4; mi++)
#pragma unroll
      for (int ni = 0; ni < 4; ni++)
        acc[mi][ni] = __builtin_amdgcn_mfma_f32_16x16x32_bf16(a[mi], b[ni], acc[mi][ni], 0, 0, 0);
    __builtin_amdgcn_s_setprio(0);
    __builtin_amdgcn_sched_barrier(0);
    __builtin_amdgcn_s_barrier();

#pragma unroll
    for (int i = 0; i < 4; i++)
      a[i] = *reinterpret_cast<const short8*>(&Ab[(wm * 128 + 64 + i * 16 + l15) * 32 + l4 * 8]);
    asm volatile("s_waitcnt lgkmcnt(0)" ::: "memory");
    __builtin_amdgcn_sched_barrier(0);
    __builtin_amdgcn_s_setprio(1);
#pragma unroll
    for (int mi = 0; mi < 4; mi++)
#pragma unroll
      for (int ni = 0; ni < 4; ni++)
        acc[mi + 4][ni] = __builtin_amdgcn_mfma_f32_16x16x32_bf16(a[mi], b[ni], acc[mi + 4][ni], 0, 0, 0);
    __builtin_amdgcn_s_setprio(0);
    __builtin_amdgcn_sched_barrier(0);

    if (t + 3 < nt) {
      asm volatile("s_waitcnt vmcnt(8)" ::: "memory");
    } else if (t + 2 < nt) {
      asm volatile("s_waitcnt vmcnt(4)" ::: "memory");
    } else if (t + 1 < nt) {
      asm volatile("s_waitcnt vmcnt(0)" ::: "memory");
    }
    __builtin_amdgcn_s_barrier();
    __builtin_amdgcn_sched_barrier(0);
  }

#pragma unroll
  for (int ni = 0; ni < 4; ni++) {
    const int col = tile_n + wn * 64 + ni * 16 + l15;
    const float bv = bias[col];
#pragma unroll
    for (int mi = 0; mi < 8; mi++) {
#pragma unroll
      for (int r = 0; r < 4; r++) {
        const int row = tile_m + wm * 128 + mi * 16 + l4 * 4 + r;
        const size_t idx = (size_t)row * N + col;
        float v = acc[mi][ni][r] + bv;
        if (EP == 0) {
          ((unsigned short*)out)[idx] = f2b(v);
        } else {
          float g = 0.5f * v * (1.0f + erff(v * 0.70710678118f));
          ((unsigned short*)out)[idx] = f2b(g);
        }
      }
    }
  }
}

// ---------------- 128^2 8-wave deep-pipelined GEMM (same schedule, no split-K) ----------------
// BM=BN=128, BK=32, 512 thr / 8 waves (2M x 4N), per-wave 64x32 out (acc 4x2).
// Waves 0-3 stage A, waves 4-7 stage B: 2 gload_lds per wave per tile -> counted
// vmcnt(4) = tiles t+2,t+3 in flight. 4-slot ring, 64 KB LDS, 2 blocks/CU.
// EP=1 epilogue: f32 out = v + bias + res  (res may alias out: each idx is
// read-once-then-written-once by exactly one thread -> replay-deterministic).
__global__ __launch_bounds__(512, 2) void gemm128_kernel(
    const unsigned short* __restrict__ A, const unsigned short* __restrict__ Bt,
    const float* __restrict__ bias, const float* __restrict__ res, float* __restrict__ out,
    int M, int N, int K, int nx) {
  extern __shared__ unsigned short lds[];
  const int tid = threadIdx.x;
  const int lane = tid & 63, w = tid >> 6;
  const int wm = w >> 2, wn = w & 3;
  const int l15 = lane & 15, l4 = lane >> 4;

  const int nwg = gridDim.x;
  int wg = blockIdx.x;
  wg = (wg & 7) * (nwg >> 3) + (wg >> 3);
  const int tile_m = (wg / nx) * 128;
  const int tile_n = (wg % nx) * 128;

  f32x4 acc[4][2] = {};

  // slot = A[128*32] + B[128*32] = 8192 ushort (16 KB); ring of 4.
  auto stage = [&](int buf, int k0) {
    unsigned short* Lb = lds + buf * 8192 + ((w < 4) ? 0 : 4096);
    const unsigned short* G = (w < 4) ? A : Bt;
    const int tbase = (w < 4) ? tile_m : tile_n;
#pragma unroll
    for (int j = 0; j < 2; j++) {
      const int chunk = (w & 3) * 128 + j * 64 + lane;   // 0..511 (16B chunks)
      const int r = chunk >> 2, c = (chunk & 3) * 8;
      __builtin_amdgcn_global_load_lds(
          (gas_ptr)&G[(size_t)(tbase + r) * K + k0 + c],
          (las_ptr)&Lb[((w & 3) * 128 + j * 64) * 8], 16, 0, 0);
    }
  };

  stage(0, 0);
  stage(1, 32);
  stage(2, 64);
  asm volatile("s_waitcnt vmcnt(4)" ::: "memory");
  __builtin_amdgcn_s_barrier();
  __builtin_amdgcn_sched_barrier(0);

  const int nt = K >> 5;
  for (int t = 0; t < nt; ++t) {
    if (t + 3 < nt) stage((t + 3) & 3, (t + 3) * 32);
    __builtin_amdgcn_sched_barrier(0);

    const unsigned short* Ab = lds + (t & 3) * 8192;
    const unsigned short* Bb = Ab + 4096;
    short8 a[2], b[2];
    // phase A: m-frags 0,1
#pragma unroll
    for (int i = 0; i < 2; i++) {
      a[i] = *reinterpret_cast<const short8*>(&Ab[(wm * 64 + i * 16 + l15) * 32 + l4 * 8]);
      b[i] = *reinterpret_cast<const short8*>(&Bb[(wn * 32 + i * 16 + l15) * 32 + l4 * 8]);
    }
    __builtin_amdgcn_s_barrier();
    asm volatile("s_waitcnt lgkmcnt(0)" ::: "memory");
    __builtin_amdgcn_sched_barrier(0);
    __builtin_amdgcn_s_setprio(1);
#pragma unroll
    for (int mi = 0; mi < 2; mi++)
#pragma unroll
      for (int ni = 0; ni < 2; ni++)
        acc[mi][ni] = __builtin_amdgcn_mfma_f32_16x16x32_bf16(a[mi], b[ni], acc[mi][ni], 0, 0, 0);
    __builtin_amdgcn_s_setprio(0);
    __builtin_amdgcn_sched_barrier(0);
    __builtin_amdgcn_s_barrier();

    // phase B: m-frags 2,3 (reuse b)
#pragma unroll
    for (int i = 0; i < 2; i++)
      a[i] = *reinterpret_cast<const short8*>(&Ab[(wm * 64 + 32 + i * 16 + l15) * 32 + l4 * 8]);
    asm volatile("s_waitcnt lgkmcnt(0)" ::: "memory");
    __builtin_amdgcn_sched_barrier(0);
    __builtin_amdgcn_s_setprio(1);
#pragma unroll
    for (int mi = 0; mi < 2; mi++)
#pragma unroll
      for (int ni = 0; ni < 2; ni++)
        acc[mi + 2][ni] = __builtin_amdgcn_mfma_f32_16x16x32_bf16(a[mi], b[ni], acc[mi + 2][ni], 0, 0, 0);
    __builtin_amdgcn_s_setprio(0);
    __builtin_amdgcn_sched_barrier(0);

    if (t + 3 < nt) {
      asm volatile("s_waitcnt vmcnt(4)" ::: "memory");
    } else if (t + 2 < nt) {
      asm volatile("s_waitcnt vmcnt(2)" ::: "memory");
    } else if (t + 1 < nt) {
      asm volatile("s_waitcnt vmcnt(0)" ::: "memory");
    }
    __builtin_amdgcn_s_barrier();
    __builtin_amdgcn_sched_barrier(0);
  }

#pragma unroll
  for (int ni = 0; ni < 2; ni++) {
    const int col = tile_n + wn * 32 + ni * 16 + l15;
    const float bv = bias[col];
#pragma unroll
    for (int mi = 0; mi < 4; mi++) {
#pragma unroll
      for (int r = 0; r < 4; r++) {
        const int row = tile_m + wm * 64 + mi * 16 + l4 * 4 + r;
        const size_t idx = (size_t)row * N + col;
        out[idx] = acc[mi][ni][r] + bv + res[idx];
      }
    }
  }
}

// ---------------- Strided-sparse flash attention v3 ----------------
// QBLK=64, grid 1024 (4 blocks/CU), 256 thr / 4 waves, each wave 16 q-rows.
__global__ __launch_bounds__(256, 4) void attn_kernel(const unsigned short* __restrict__ qkv,
                                                      unsigned short* __restrict__ y) {
  __shared__ unsigned short SH[17408];   // 34816 B
  const int tid = threadIdx.x;
  const int lane = tid & 63, w = tid >> 6;
  const int l15 = lane & 15, l4 = lane >> 4;

  const int bi = blockIdx.x;
  const int quarter = bi >> 8, rest = bi & 255;
  const int bh = rest >> 3, sub = rest & 7;
  int qt;
  if (quarter == 0) qt = sub;
  else if (quarter == 1) qt = 15 - sub;
  else if (quarter == 2) qt = 16 + sub;
  else qt = 31 - sub;
  const int bb = bh >> 4, hh = bh & 15;
  const int q0 = qt * 64;
  const size_t base = (size_t)bb * Tn * (3 * Cn) + hh * 64;

  const int nfar = qt >> 1;                    // far tiles: 64 even keys each
  const int ntiles = nfar + (q0 ? 2 : 1);

  unsigned short* Vt = SH + 8192;              // [64 d][72], swizzled key index
  unsigned short* Ps = SH + 12800 + w * 1152;  // per-wave [16][72]

  auto keyof = [&](int t, int row) -> int {
    if (t < nfar) return t * 128 + 2 * row;    // gathered even keys
    return q0 - 64 * (ntiles - 1 - t) + row;   // near tiles, ascending
  };
  auto stageK = [&](int t) {
    unsigned short* kb = SH + ((t & 1) << 12);
#pragma unroll
    for (int u = 0; u < 2; u++) {
      const int chunk = u * 256 + tid;
      const int row = chunk >> 3, cc = chunk & 7;
      const int csrc = cc ^ (row & 7);         // pre-swizzled source, linear dest
      const int key = keyof(t, row);
      __builtin_amdgcn_global_load_lds(
          (gas_ptr)&qkv[base + Cn + (size_t)key * (3 * Cn) + csrc * 8],
          (las_ptr)&kb[(u * 256 + (w << 6)) * 8], 16, 0, 0);
    }
  };
  uint4 vr[2];
  auto fetchV = [&](int t) {
#pragma unroll
    for (int u = 0; u < 2; u++) {
      const int chunk = u * 256 + tid;
      const int row = chunk >> 3, cc = chunk & 7;
      const int key = keyof(t, row);
      vr[u] = *reinterpret_cast<const uint4*>(&qkv[base + 2 * Cn + (size_t)key * (3 * Cn) + cc * 8]);
    }
  };

  // ---- prologue: Q -> SH[0,4096) (pre-swizzled gload), hoist, then reuse as Kbuf0
#pragma unroll
  for (int u = 0; u < 2; u++) {
    const int chunk = u * 256 + tid;
    const int row = chunk >> 3, cc = chunk & 7;
    const int csrc = cc ^ (row & 7);
    __builtin_amdgcn_global_load_lds(
        (gas_ptr)&qkv[base + (size_t)(q0 + row) * (3 * Cn) + csrc * 8],
        (las_ptr)&SH[(u * 256 + (w << 6)) * 8], 16, 0, 0);
  }
  __syncthreads();
  short8 qf[2];
#pragma unroll
  for (int ks = 0; ks < 2; ks++) {
    const int r = (w << 4) + l15;
    qf[ks] = *reinterpret_cast<const short8*>(&SH[r * 64 + (((ks * 4 + l4) ^ (l15 & 7)) * 8)]);
  }
  asm volatile("s_waitcnt lgkmcnt(0)" ::: "memory");   // all waves done reading Qs
  __builtin_amdgcn_s_barrier();
  __builtin_amdgcn_sched_barrier(0);
  stageK(0);
  fetchV(0);
  __syncthreads();                                     // K0 + vr0 landed

  f32x4 acc_o[4] = {};
  float mrow[4], lrow[4];
#pragma unroll
  for (int r = 0; r < 4; r++) { mrow[r] = -1e30f; lrow[r] = 0.0f; }

  for (int t = 0; t < ntiles; ++t) {
    // 1. write V(t) (swizzled transpose; write pattern covers all 32 banks)
#pragma unroll
    for (int u = 0; u < 2; u++) {
      const int chunk = u * 256 + tid;
      const int row = chunk >> 3, cc = chunk & 7;
      unsigned short tmp[8];
      *reinterpret_cast<uint4*>(tmp) = vr[u];
      const int xr = row ^ (cc << 3);
#pragma unroll
      for (int j = 0; j < 8; j++) Vt[(cc * 8 + j) * 72 + xr] = tmp[j];
    }
    // 2. prefetch t+1 (stays in flight across compute — drains at end-sync)
    if (t + 1 < ntiles) { stageK(t + 1); fetchV(t + 1); }
    // 3. mid barrier: V visible; NO vmcnt drain
    asm volatile("s_waitcnt lgkmcnt(0)" ::: "memory");
    __builtin_amdgcn_s_barrier();
    __builtin_amdgcn_sched_barrier(0);

    // 4. compute
    const unsigned short* Kb = SH + ((t & 1) << 12);
    f32x4 s[4] = {};
#pragma unroll
    for (int ni = 0; ni < 4; ni++) {
#pragma unroll
      for (int ks = 0; ks < 2; ks++) {
        const int r = ni * 16 + l15;
        short8 kf = *reinterpret_cast<const short8*>(&Kb[r * 64 + (((ks * 4 + l4) ^ (l15 & 7)) * 8)]);
        s[ni] = __builtin_amdgcn_mfma_f32_16x16x32_bf16(qf[ks], kf, s[ni], 0, 0, 0);
      }
    }

    const bool far = (t < nfar);
    const int kb0 = far ? t * 128 : q0 - 64 * (ntiles - 1 - t);
#pragma unroll
    for (int ni = 0; ni < 4; ni++) {
      const int pos = ni * 16 + l15;
      const int j = far ? kb0 + 2 * pos : kb0 + pos;
#pragma unroll
      for (int r = 0; r < 4; r++) {
        float v = s[ni][r] * 0.125f;
        if (far) {
          v = (j < q0 - 64) ? v : -1e30f;
        } else {
          const int iq = q0 + (w << 4) + l4 * 4 + r;
          const bool ok = (j <= iq) && ((j >= iq - 4) || ((j & 1) == 0));
          v = ok ? v : -1e30f;
        }
        s[ni][r] = v;
      }
    }

    // online softmax
#pragma unroll
    for (int r = 0; r < 4; r++) {
      float tm = fmaxf(fmaxf(s[0][r], s[1][r]), fmaxf(s[2][r], s[3][r]));
      tm = fmaxf(tm, __shfl_xor(tm, 1));
      tm = fmaxf(tm, __shfl_xor(tm, 2));
      tm = fmaxf(tm, __shfl_xor(tm, 4));
      tm = fmaxf(tm, __shfl_xor(tm, 8));
      const float mnew = fmaxf(mrow[r], tm);
      const float alpha = __expf(mrow[r] - mnew);
      mrow[r] = mnew;
      lrow[r] *= alpha;
#pragma unroll
      for (int nd = 0; nd < 4; nd++) acc_o[nd][r] *= alpha;
      float rs = 0.0f;
#pragma unroll
      for (int ni = 0; ni < 4; ni++) {
        const float pv = __expf(s[ni][r] - mnew);
        s[ni][r] = pv;
        rs += pv;
      }
      rs += __shfl_xor(rs, 1); rs += __shfl_xor(rs, 2);
      rs += __shfl_xor(rs, 4); rs += __shfl_xor(rs, 8);
      lrow[r] += rs;
    }

    // P -> LDS (C-layout to A-layout), wave-private
#pragma unroll
    for (int ni = 0; ni < 4; ni++)
#pragma unroll
      for (int r = 0; r < 4; r++)
        Ps[(l4 * 4 + r) * 72 + ni * 16 + l15] = f2b(s[ni][r]);

    // O += P @ V
#pragma unroll
    for (int kss = 0; kss < 2; kss++) {
      short8 pf = *reinterpret_cast<const short8*>(&Ps[l15 * 72 + kss * 32 + l4 * 8]);
#pragma unroll
      for (int nd = 0; nd < 4; nd++) {
        const int d = nd * 16 + l15;
        const int kcol = (kss * 32 + l4 * 8) ^ ((d >> 3) << 3);
        short8 vf = *reinterpret_cast<const short8*>(&Vt[d * 72 + kcol]);
        acc_o[nd] = __builtin_amdgcn_mfma_f32_16x16x32_bf16(pf, vf, acc_o[nd], 0, 0, 0);
      }
    }

    // 5. end barrier: LDS reads done for reuse; vmcnt drained -> K(t+1)/vr(t+1) ready
    __syncthreads();
  }

  // normalize + write y
#pragma unroll
  for (int r = 0; r < 4; r++) {
    const float inv = 1.0f / lrow[r];
    const int row = q0 + (w << 4) + l4 * 4 + r;
#pragma unroll
    for (int nd = 0; nd < 4; nd++) {
      const int col = nd * 16 + l15;
      y[((size_t)bb * Tn + row) * Cn + hh * 64 + col] = f2b(acc_o[nd][r] * inv);
    }
  }
}

// ---------------- launch ----------------
extern "C" void kernel_launch(void* const* d_in, const int* in_sizes, int n_in,
                              void* d_out, int out_size, void* d_ws, size_t ws_size,
                              hipStream_t stream) {
  const float* x           = (const float*)d_in[0];
  const float* ln1_w       = (const float*)d_in[1];
  const float* ln1_b       = (const float*)d_in[2];
  const float* c_attn_w    = (const float*)d_in[3];
  const float* c_attn_b    = (const float*)d_in[4];
  const float* attn_proj_w = (const float*)d_in[5];
  const float* attn_proj_b = (const float*)d_in[6];
  const float* ln2_w       = (const float*)d_in[7];
  const float* ln2_b       = (const float*)d_in[8];
  const float* fc_w        = (const float*)d_in[9];
  const float* fc_b        = (const float*)d_in[10];
  const float* mlp_proj_w  = (const float*)d_in[11];
  const float* mlp_proj_b  = (const float*)d_in[12];
  float* out = (float*)d_out;

  char* ws = (char*)d_ws;
  unsigned short* wT1 = (unsigned short*)(ws);                     // [3072][1024]
  unsigned short* wT2 = (unsigned short*)(ws + 6291456);           // [1024][1024]
  unsigned short* wT3 = (unsigned short*)(ws + 8388608);           // [4096][1024]
  unsigned short* wT4 = (unsigned short*)(ws + 16777216);          // [1024][4096]
  unsigned short* h   = (unsigned short*)(ws + 25165824);          // [4096][1024]
  unsigned short* qkv = (unsigned short*)(ws + 33554432);          // [4096][3072] / [4096][4096]
  unsigned short* yb  = (unsigned short*)(ws + 67108864);          // [4096][1024]

  hipFuncSetAttribute((const void*)gemm256_kernel<0>, hipFuncAttributeMaxDynamicSharedMemorySize, 131072);
  hipFuncSetAttribute((const void*)gemm256_kernel<2>, hipFuncAttributeMaxDynamicSharedMemorySize, 131072);
  hipFuncSetAttribute((const void*)gemm128_kernel, hipFuncAttributeMaxDynamicSharedMemorySize, 65536);

  transpose_bf16_kernel<<<dim3(3072 / 32, 1024 / 32), 256, 0, stream>>>(c_attn_w, wT1, 1024, 3072);
  transpose_bf16_kernel<<<dim3(1024 / 32, 1024 / 32), 256, 0, stream>>>(attn_proj_w, wT2, 1024, 1024);
  transpose_bf16_kernel<<<dim3(4096 / 32, 1024 / 32), 256, 0, stream>>>(fc_w, wT3, 1024, 4096);
  transpose_bf16_kernel<<<dim3(1024 / 32, 4096 / 32), 256, 0, stream>>>(mlp_proj_w, wT4, 4096, 1024);

  // LN1
  ln_kernel<<<Mrows, 256, 0, stream>>>(x, ln1_w, ln1_b, h);
  // qkv = h @ c_attn_w + b   [4096, 3072]
  gemm256_kernel<0><<<(Mrows / 256) * (3072 / 256), 512, 131072, stream>>>(
      h, wT1, c_attn_b, qkv, Mrows, 3072, 1024, 3072 / 256);
  // attention -> y  (1024 blocks, complementary qt balance)
  attn_kernel<<<1024, 256, 0, stream>>>(qkv, yb);
  // x1 = x + y @ attn_proj_w + b   grid 32x8 = 256, no split-K, no atomics
  gemm128_kernel<<<(Mrows / 128) * (1024 / 128), 512, 65536, stream>>>(
      yb, wT2, attn_proj_b, x, out, Mrows, 1024, 1024, 1024 / 128);
  // LN2 on x1
  ln_kernel<<<Mrows, 256, 0, stream>>>(out, ln2_w, ln2_b, h);
  // a = gelu(h2 @ fc_w + b)   [4096, 4096]
  gemm256_kernel<2><<<(Mrows / 256) * (4096 / 256), 512, 131072, stream>>>(
      h, wT3, fc_b, qkv, Mrows, 4096, 1024, 4096 / 256);
  // out = x1 + a @ mlp_proj_w + b   (in-place res: read-once-write-once per idx)
  gemm128_kernel<<<(Mrows / 128) * (1024 / 128), 512, 65536, stream>>>(
      qkv, wT4, mlp_proj_b, out, out, Mrows, 1024, 4096, 1024 / 128);
}

// Round 10
// 247.195 us; speedup vs baseline: 1.4243x; 1.0366x over previous
//
#include <hip/hip_runtime.h>
#include <hip/hip_bf16.h>

#define Bn 2
#define Tn 2048
#define Cn 1024
#define Hn 16
#define Dn 64
#define Mrows (Bn * Tn)   // 4096

typedef __attribute__((ext_vector_type(8))) short short8;
typedef __attribute__((ext_vector_type(4))) float f32x4;

typedef const __attribute__((address_space(1))) unsigned int* gas_ptr;
typedef __attribute__((address_space(3))) unsigned int* las_ptr;

__device__ __forceinline__ unsigned short f2b(float f) {
  unsigned int u = __builtin_bit_cast(unsigned int, f);
  return (unsigned short)((u + 0x7fffu + ((u >> 16) & 1u)) >> 16);
}

// ---------------- LayerNorm: f32 in -> bf16 out ----------------
__global__ __launch_bounds__(256) void ln_kernel(const float* __restrict__ x,
                                                 const float* __restrict__ w,
                                                 const float* __restrict__ b,
                                                 unsigned short* __restrict__ out) {
  const int row = blockIdx.x;
  const int t = threadIdx.x;
  const float4 v = *reinterpret_cast<const float4*>(x + (size_t)row * Cn + t * 4);
  float s = v.x + v.y + v.z + v.w;
  float s2 = v.x * v.x + v.y * v.y + v.z * v.z + v.w * v.w;
#pragma unroll
  for (int m = 1; m < 64; m <<= 1) { s += __shfl_xor(s, m); s2 += __shfl_xor(s2, m); }
  __shared__ float ls[4], ls2[4];
  if ((t & 63) == 0) { ls[t >> 6] = s; ls2[t >> 6] = s2; }
  __syncthreads();
  s  = ls[0] + ls[1] + ls[2] + ls[3];
  s2 = ls2[0] + ls2[1] + ls2[2] + ls2[3];
  const float mu = s * (1.0f / Cn);
  const float rstd = rsqrtf(s2 * (1.0f / Cn) - mu * mu + 1e-5f);
  const float4 wv = *reinterpret_cast<const float4*>(w + t * 4);
  const float4 bv = *reinterpret_cast<const float4*>(b + t * 4);
  unsigned short o[4];
  o[0] = f2b((v.x - mu) * rstd * wv.x + bv.x);
  o[1] = f2b((v.y - mu) * rstd * wv.y + bv.y);
  o[2] = f2b((v.z - mu) * rstd * wv.z + bv.z);
  o[3] = f2b((v.w - mu) * rstd * wv.w + bv.w);
  *reinterpret_cast<uint2*>(out + (size_t)row * Cn + t * 4) = *reinterpret_cast<uint2*>(o);
}

// ---------------- Transpose + f32->bf16: W[K][N] -> Wt[N][K] ----------------
__global__ __launch_bounds__(256) void transpose_bf16_kernel(const float* __restrict__ W,
                                                             unsigned short* __restrict__ Wt,
                                                             int K, int N) {
  __shared__ float tile[32][33];
  const int n0 = blockIdx.x * 32, k0 = blockIdx.y * 32;
  const int tx = threadIdx.x & 31, ty = threadIdx.x >> 5;  // ty 0..7
#pragma unroll
  for (int r = 0; r < 4; r++)
    tile[ty + r * 8][tx] = W[(size_t)(k0 + ty + r * 8) * N + n0 + tx];
  __syncthreads();
#pragma unroll
  for (int r = 0; r < 4; r++)
    Wt[(size_t)(n0 + ty + r * 8) * K + k0 + tx] = f2b(tile[tx][ty + r * 8]);
}

// ---------------- 256^2 8-wave deep-pipelined GEMM (m201-style) ----------------
// R10: staging addresses strength-reduced (4 per-thread base pointers + t*32
// element offset), K-loop unrolled x4 so ring-slot indices are compile-time.
// Sync schedule identical to the R6-verified structure.
// EP=0: bf16 = v+bias; EP=2: bf16 = gelu(v+bias)
#define BUFS 16384
template <int EP>
__global__ __launch_bounds__(512, 2) void gemm256_kernel(
    const unsigned short* __restrict__ A, const unsigned short* __restrict__ Bt,
    const float* __restrict__ bias, void* out, int M, int N, int K, int nx) {
  extern __shared__ unsigned short lds[];
  const int tid = threadIdx.x;
  const int lane = tid & 63, w = tid >> 6;
  const int wm = w >> 2, wn = w & 3;
  const int l15 = lane & 15, l4 = lane >> 4;

  const int nwg = gridDim.x;
  int wg = blockIdx.x;
  wg = (wg & 7) * (nwg >> 3) + (wg >> 3);
  const int tile_m = (wg / nx) * 256;
  const int tile_n = (wg % nx) * 256;

  f32x4 acc[8][4] = {};

  // ---- invariant staging bases (chunk = r*4 + c16; LDS linear == chunk order)
  const int ch0 = w * 64 + lane;                  // j=0 chunk 0..511
  const int r0 = ch0 >> 2, c0 = (ch0 & 3) * 8;    // row 0..127, col-offset
  const unsigned short* gA0 = A + (size_t)(tile_m + r0) * K + c0;
  const unsigned short* gA1 = gA0 + (size_t)128 * K;   // j=1: row+128
  const unsigned short* gB0 = Bt + (size_t)(tile_n + r0) * K + c0;
  const unsigned short* gB1 = gB0 + (size_t)128 * K;
  const int ldsA0 = (w * 64) * 8, ldsA1 = (512 + w * 64) * 8;

  auto stage = [&](unsigned short* Ab, int t) {
    unsigned short* Bb = Ab + 8192;
    const size_t ko = (size_t)t * 32;             // 32 ushorts = 64 B per K-tile
    __builtin_amdgcn_global_load_lds((gas_ptr)(gA0 + ko), (las_ptr)&Ab[ldsA0], 16, 0, 0);
    __builtin_amdgcn_global_load_lds((gas_ptr)(gA1 + ko), (las_ptr)&Ab[ldsA1], 16, 0, 0);
    __builtin_amdgcn_global_load_lds((gas_ptr)(gB0 + ko), (las_ptr)&Bb[ldsA0], 16, 0, 0);
    __builtin_amdgcn_global_load_lds((gas_ptr)(gB1 + ko), (las_ptr)&Bb[ldsA1], 16, 0, 0);
  };

  stage(lds, 0);
  stage(lds + BUFS, 1);
  stage(lds + 2 * BUFS, 2);
  asm volatile("s_waitcnt vmcnt(8)" ::: "memory");
  __builtin_amdgcn_s_barrier();
  __builtin_amdgcn_sched_barrier(0);

  const int nt = K >> 5;                          // multiple of 4 at all call sites
  for (int tb = 0; tb < nt; tb += 4) {
#pragma unroll
    for (int u = 0; u < 4; u++) {
      const int t = tb + u;                       // slot = t&3 = u (tb % 4 == 0)
      if (t + 3 < nt) stage(lds + (((u + 3) & 3) * BUFS), t + 3);
      __builtin_amdgcn_sched_barrier(0);

      const unsigned short* Ab = lds + u * BUFS;
      const unsigned short* Bb = Ab + 8192;
      short8 a[4], b[4];
#pragma unroll
      for (int i = 0; i < 4; i++) {
        a[i] = *reinterpret_cast<const short8*>(&Ab[(wm * 128 + i * 16 + l15) * 32 + l4 * 8]);
        b[i] = *reinterpret_cast<const short8*>(&Bb[(wn * 64 + i * 16 + l15) * 32 + l4 * 8]);
      }
      __builtin_amdgcn_s_barrier();
      asm volatile("s_waitcnt lgkmcnt(0)" ::: "memory");
      __builtin_amdgcn_sched_barrier(0);
      __builtin_amdgcn_s_setprio(1);
#pragma unroll
      for (int mi = 0; mi < 4; mi++)
#pragma unroll
        for (int ni = 0; ni < 4; ni++)
          acc[mi][ni] = __builtin_amdgcn_mfma_f32_16x16x32_bf16(a[mi], b[ni], acc[mi][ni], 0, 0, 0);
      __builtin_amdgcn_s_setprio(0);
      __builtin_amdgcn_sched_barrier(0);
      __builtin_amdgcn_s_barrier();

#pragma unroll
      for (int i = 0; i < 4; i++)
        a[i] = *reinterpret_cast<const short8*>(&Ab[(wm * 128 + 64 + i * 16 + l15) * 32 + l4 * 8]);
      asm volatile("s_waitcnt lgkmcnt(0)" ::: "memory");
      __builtin_amdgcn_sched_barrier(0);
      __builtin_amdgcn_s_setprio(1);
#pragma unroll
      for (int mi = 0; mi < 4; mi++)
#pragma unroll
        for (int ni = 0; ni < 4; ni++)
          acc[mi + 4][ni] = __builtin_amdgcn_mfma_f32_16x16x32_bf16(a[mi], b[ni], acc[mi + 4][ni], 0, 0, 0);
      __builtin_amdgcn_s_setprio(0);
      __builtin_amdgcn_sched_barrier(0);

      if (t + 3 < nt) {
        asm volatile("s_waitcnt vmcnt(8)" ::: "memory");
      } else if (t + 2 < nt) {
        asm volatile("s_waitcnt vmcnt(4)" ::: "memory");
      } else if (t + 1 < nt) {
        asm volatile("s_waitcnt vmcnt(0)" ::: "memory");
      }
      __builtin_amdgcn_s_barrier();
      __builtin_amdgcn_sched_barrier(0);
    }
  }

#pragma unroll
  for (int ni = 0; ni < 4; ni++) {
    const int col = tile_n + wn * 64 + ni * 16 + l15;
    const float bv = bias[col];
#pragma unroll
    for (int mi = 0; mi < 8; mi++) {
#pragma unroll
      for (int r = 0; r < 4; r++) {
        const int row = tile_m + wm * 128 + mi * 16 + l4 * 4 + r;
        const size_t idx = (size_t)row * N + col;
        float v = acc[mi][ni][r] + bv;
        if (EP == 0) {
          ((unsigned short*)out)[idx] = f2b(v);
        } else {
          float g = 0.5f * v * (1.0f + erff(v * 0.70710678118f));
          ((unsigned short*)out)[idx] = f2b(g);
        }
      }
    }
  }
}

// ---------------- 128^2 8-wave deep-pipelined GEMM (no split-K) ----------------
// Same R10 treatment: invariant bases + x4 unroll. EP: f32 out = v + bias + res
// (res may alias out: read-once-then-written-once per idx by one thread).
__global__ __launch_bounds__(512, 2) void gemm128_kernel(
    const unsigned short* __restrict__ A, const unsigned short* __restrict__ Bt,
    const float* __restrict__ bias, const float* __restrict__ res, float* __restrict__ out,
    int M, int N, int K, int nx) {
  extern __shared__ unsigned short lds[];
  const int tid = threadIdx.x;
  const int lane = tid & 63, w = tid >> 6;
  const int wm = w >> 2, wn = w & 3;
  const int l15 = lane & 15, l4 = lane >> 4;

  const int nwg = gridDim.x;
  int wg = blockIdx.x;
  wg = (wg & 7) * (nwg >> 3) + (wg >> 3);
  const int tile_m = (wg / nx) * 128;
  const int tile_n = (wg % nx) * 128;

  f32x4 acc[4][2] = {};

  // waves 0-3 stage A, 4-7 stage B; 2 chunks per thread per tile.
  const unsigned short* Gs = (w < 4) ? A : Bt;
  const int tb0 = (w < 4) ? tile_m : tile_n;
  const int ch0 = (w & 3) * 128 + lane;           // j=0 chunk
  const int ch1 = ch0 + 64;
  const unsigned short* g0 = Gs + (size_t)(tb0 + (ch0 >> 2)) * K + (ch0 & 3) * 8;
  const unsigned short* g1 = Gs + (size_t)(tb0 + (ch1 >> 2)) * K + (ch1 & 3) * 8;
  const int lds0 = ((w & 3) * 128) * 8, lds1 = ((w & 3) * 128 + 64) * 8;
  const int half = (w < 4) ? 0 : 4096;

  auto stage = [&](unsigned short* slot, int t) {
    unsigned short* Lb = slot + half;
    const size_t ko = (size_t)t * 32;
    __builtin_amdgcn_global_load_lds((gas_ptr)(g0 + ko), (las_ptr)&Lb[lds0], 16, 0, 0);
    __builtin_amdgcn_global_load_lds((gas_ptr)(g1 + ko), (las_ptr)&Lb[lds1], 16, 0, 0);
  };

  stage(lds, 0);
  stage(lds + 8192, 1);
  stage(lds + 16384, 2);
  asm volatile("s_waitcnt vmcnt(4)" ::: "memory");
  __builtin_amdgcn_s_barrier();
  __builtin_amdgcn_sched_barrier(0);

  const int nt = K >> 5;                          // 32 or 128
  for (int tb = 0; tb < nt; tb += 4) {
#pragma unroll
    for (int u = 0; u < 4; u++) {
      const int t = tb + u;
      if (t + 3 < nt) stage(lds + ((u + 3) & 3) * 8192, t + 3);
      __builtin_amdgcn_sched_barrier(0);

      const unsigned short* Ab = lds + u * 8192;
      const unsigned short* Bb = Ab + 4096;
      short8 a[2], b[2];
#pragma unroll
      for (int i = 0; i < 2; i++) {
        a[i] = *reinterpret_cast<const short8*>(&Ab[(wm * 64 + i * 16 + l15) * 32 + l4 * 8]);
        b[i] = *reinterpret_cast<const short8*>(&Bb[(wn * 32 + i * 16 + l15) * 32 + l4 * 8]);
      }
      __builtin_amdgcn_s_barrier();
      asm volatile("s_waitcnt lgkmcnt(0)" ::: "memory");
      __builtin_amdgcn_sched_barrier(0);
      __builtin_amdgcn_s_setprio(1);
#pragma unroll
      for (int mi = 0; mi < 2; mi++)
#pragma unroll
        for (int ni = 0; ni < 2; ni++)
          acc[mi][ni] = __builtin_amdgcn_mfma_f32_16x16x32_bf16(a[mi], b[ni], acc[mi][ni], 0, 0, 0);
      __builtin_amdgcn_s_setprio(0);
      __builtin_amdgcn_sched_barrier(0);
      __builtin_amdgcn_s_barrier();

#pragma unroll
      for (int i = 0; i < 2; i++)
        a[i] = *reinterpret_cast<const short8*>(&Ab[(wm * 64 + 32 + i * 16 + l15) * 32 + l4 * 8]);
      asm volatile("s_waitcnt lgkmcnt(0)" ::: "memory");
      __builtin_amdgcn_sched_barrier(0);
      __builtin_amdgcn_s_setprio(1);
#pragma unroll
      for (int mi = 0; mi < 2; mi++)
#pragma unroll
        for (int ni = 0; ni < 2; ni++)
          acc[mi + 2][ni] = __builtin_amdgcn_mfma_f32_16x16x32_bf16(a[mi], b[ni], acc[mi + 2][ni], 0, 0, 0);
      __builtin_amdgcn_s_setprio(0);
      __builtin_amdgcn_sched_barrier(0);

      if (t + 3 < nt) {
        asm volatile("s_waitcnt vmcnt(4)" ::: "memory");
      } else if (t + 2 < nt) {
        asm volatile("s_waitcnt vmcnt(2)" ::: "memory");
      } else if (t + 1 < nt) {
        asm volatile("s_waitcnt vmcnt(0)" ::: "memory");
      }
      __builtin_amdgcn_s_barrier();
      __builtin_amdgcn_sched_barrier(0);
    }
  }

#pragma unroll
  for (int ni = 0; ni < 2; ni++) {
    const int col = tile_n + wn * 32 + ni * 16 + l15;
    const float bv = bias[col];
#pragma unroll
    for (int mi = 0; mi < 4; mi++) {
#pragma unroll
      for (int r = 0; r < 4; r++) {
        const int row = tile_m + wm * 64 + mi * 16 + l4 * 4 + r;
        const size_t idx = (size_t)row * N + col;
        out[idx] = acc[mi][ni][r] + bv + res[idx];
      }
    }
  }
}

// ---------------- Strided-sparse flash attention v3 (unchanged from R9) ----------------
__global__ __launch_bounds__(256, 4) void attn_kernel(const unsigned short* __restrict__ qkv,
                                                      unsigned short* __restrict__ y) {
  __shared__ unsigned short SH[17408];   // 34816 B
  const int tid = threadIdx.x;
  const int lane = tid & 63, w = tid >> 6;
  const int l15 = lane & 15, l4 = lane >> 4;

  const int bi = blockIdx.x;
  const int quarter = bi >> 8, rest = bi & 255;
  const int bh = rest >> 3, sub = rest & 7;
  int qt;
  if (quarter == 0) qt = sub;
  else if (quarter == 1) qt = 15 - sub;
  else if (quarter == 2) qt = 16 + sub;
  else qt = 31 - sub;
  const int bb = bh >> 4, hh = bh & 15;
  const int q0 = qt * 64;
  const size_t base = (size_t)bb * Tn * (3 * Cn) + hh * 64;

  const int nfar = qt >> 1;
  const int ntiles = nfar + (q0 ? 2 : 1);

  unsigned short* Vt = SH + 8192;
  unsigned short* Ps = SH + 12800 + w * 1152;

  auto keyof = [&](int t, int row) -> int {
    if (t < nfar) return t * 128 + 2 * row;
    return q0 - 64 * (ntiles - 1 - t) + row;
  };
  auto stageK = [&](int t) {
    unsigned short* kb = SH + ((t & 1) << 12);
#pragma unroll
    for (int u = 0; u < 2; u++) {
      const int chunk = u * 256 + tid;
      const int row = chunk >> 3, cc = chunk & 7;
      const int csrc = cc ^ (row & 7);
      const int key = keyof(t, row);
      __builtin_amdgcn_global_load_lds(
          (gas_ptr)&qkv[base + Cn + (size_t)key * (3 * Cn) + csrc * 8],
          (las_ptr)&kb[(u * 256 + (w << 6)) * 8], 16, 0, 0);
    }
  };
  uint4 vr[2];
  auto fetchV = [&](int t) {
#pragma unroll
    for (int u = 0; u < 2; u++) {
      const int chunk = u * 256 + tid;
      const int row = chunk >> 3, cc = chunk & 7;
      const int key = keyof(t, row);
      vr[u] = *reinterpret_cast<const uint4*>(&qkv[base + 2 * Cn + (size_t)key * (3 * Cn) + cc * 8]);
    }
  };

#pragma unroll
  for (int u = 0; u < 2; u++) {
    const int chunk = u * 256 + tid;
    const int row = chunk >> 3, cc = chunk & 7;
    const int csrc = cc ^ (row & 7);
    __builtin_amdgcn_global_load_lds(
        (gas_ptr)&qkv[base + (size_t)(q0 + row) * (3 * Cn) + csrc * 8],
        (las_ptr)&SH[(u * 256 + (w << 6)) * 8], 16, 0, 0);
  }
  __syncthreads();
  short8 qf[2];
#pragma unroll
  for (int ks = 0; ks < 2; ks++) {
    const int r = (w << 4) + l15;
    qf[ks] = *reinterpret_cast<const short8*>(&SH[r * 64 + (((ks * 4 + l4) ^ (l15 & 7)) * 8)]);
  }
  asm volatile("s_waitcnt lgkmcnt(0)" ::: "memory");
  __builtin_amdgcn_s_barrier();
  __builtin_amdgcn_sched_barrier(0);
  stageK(0);
  fetchV(0);
  __syncthreads();

  f32x4 acc_o[4] = {};
  float mrow[4], lrow[4];
#pragma unroll
  for (int r = 0; r < 4; r++) { mrow[r] = -1e30f; lrow[r] = 0.0f; }

  for (int t = 0; t < ntiles; ++t) {
#pragma unroll
    for (int u = 0; u < 2; u++) {
      const int chunk = u * 256 + tid;
      const int row = chunk >> 3, cc = chunk & 7;
      unsigned short tmp[8];
      *reinterpret_cast<uint4*>(tmp) = vr[u];
      const int xr = row ^ (cc << 3);
#pragma unroll
      for (int j = 0; j < 8; j++) Vt[(cc * 8 + j) * 72 + xr] = tmp[j];
    }
    if (t + 1 < ntiles) { stageK(t + 1); fetchV(t + 1); }
    asm volatile("s_waitcnt lgkmcnt(0)" ::: "memory");
    __builtin_amdgcn_s_barrier();
    __builtin_amdgcn_sched_barrier(0);

    const unsigned short* Kb = SH + ((t & 1) << 12);
    f32x4 s[4] = {};
#pragma unroll
    for (int ni = 0; ni < 4; ni++) {
#pragma unroll
      for (int ks = 0; ks < 2; ks++) {
        const int r = ni * 16 + l15;
        short8 kf = *reinterpret_cast<const short8*>(&Kb[r * 64 + (((ks * 4 + l4) ^ (l15 & 7)) * 8)]);
        s[ni] = __builtin_amdgcn_mfma_f32_16x16x32_bf16(qf[ks], kf, s[ni], 0, 0, 0);
      }
    }

    const bool far = (t < nfar);
    const int kb0 = far ? t * 128 : q0 - 64 * (ntiles - 1 - t);
#pragma unroll
    for (int ni = 0; ni < 4; ni++) {
      const int pos = ni * 16 + l15;
      const int j = far ? kb0 + 2 * pos : kb0 + pos;
#pragma unroll
      for (int r = 0; r < 4; r++) {
        float v = s[ni][r] * 0.125f;
        if (far) {
          v = (j < q0 - 64) ? v : -1e30f;
        } else {
          const int iq = q0 + (w << 4) + l4 * 4 + r;
          const bool ok = (j <= iq) && ((j >= iq - 4) || ((j & 1) == 0));
          v = ok ? v : -1e30f;
        }
        s[ni][r] = v;
      }
    }

#pragma unroll
    for (int r = 0; r < 4; r++) {
      float tm = fmaxf(fmaxf(s[0][r], s[1][r]), fmaxf(s[2][r], s[3][r]));
      tm = fmaxf(tm, __shfl_xor(tm, 1));
      tm = fmaxf(tm, __shfl_xor(tm, 2));
      tm = fmaxf(tm, __shfl_xor(tm, 4));
      tm = fmaxf(tm, __shfl_xor(tm, 8));
      const float mnew = fmaxf(mrow[r], tm);
      const float alpha = __expf(mrow[r] - mnew);
      mrow[r] = mnew;
      lrow[r] *= alpha;
#pragma unroll
      for (int nd = 0; nd < 4; nd++) acc_o[nd][r] *= alpha;
      float rs = 0.0f;
#pragma unroll
      for (int ni = 0; ni < 4; ni++) {
        const float pv = __expf(s[ni][r] - mnew);
        s[ni][r] = pv;
        rs += pv;
      }
      rs += __shfl_xor(rs, 1); rs += __shfl_xor(rs, 2);
      rs += __shfl_xor(rs, 4); rs += __shfl_xor(rs, 8);
      lrow[r] += rs;
    }

#pragma unroll
    for (int ni = 0; ni < 4; ni++)
#pragma unroll
      for (int r = 0; r < 4; r++)
        Ps[(l4 * 4 + r) * 72 + ni * 16 + l15] = f2b(s[ni][r]);

#pragma unroll
    for (int kss = 0; kss < 2; kss++) {
      short8 pf = *reinterpret_cast<const short8*>(&Ps[l15 * 72 + kss * 32 + l4 * 8]);
#pragma unroll
      for (int nd = 0; nd < 4; nd++) {
        const int d = nd * 16 + l15;
        const int kcol = (kss * 32 + l4 * 8) ^ ((d >> 3) << 3);
        short8 vf = *reinterpret_cast<const short8*>(&Vt[d * 72 + kcol]);
        acc_o[nd] = __builtin_amdgcn_mfma_f32_16x16x32_bf16(pf, vf, acc_o[nd], 0, 0, 0);
      }
    }

    __syncthreads();
  }

#pragma unroll
  for (int r = 0; r < 4; r++) {
    const float inv = 1.0f / lrow[r];
    const int row = q0 + (w << 4) + l4 * 4 + r;
#pragma unroll
    for (int nd = 0; nd < 4; nd++) {
      const int col = nd * 16 + l15;
      y[((size_t)bb * Tn + row) * Cn + hh * 64 + col] = f2b(acc_o[nd][r] * inv);
    }
  }
}

// ---------------- launch ----------------
extern "C" void kernel_launch(void* const* d_in, const int* in_sizes, int n_in,
                              void* d_out, int out_size, void* d_ws, size_t ws_size,
                              hipStream_t stream) {
  const float* x           = (const float*)d_in[0];
  const float* ln1_w       = (const float*)d_in[1];
  const float* ln1_b       = (const float*)d_in[2];
  const float* c_attn_w    = (const float*)d_in[3];
  const float* c_attn_b    = (const float*)d_in[4];
  const float* attn_proj_w = (const float*)d_in[5];
  const float* attn_proj_b = (const float*)d_in[6];
  const float* ln2_w       = (const float*)d_in[7];
  const float* ln2_b       = (const float*)d_in[8];
  const float* fc_w        = (const float*)d_in[9];
  const float* fc_b        = (const float*)d_in[10];
  const float* mlp_proj_w  = (const float*)d_in[11];
  const float* mlp_proj_b  = (const float*)d_in[12];
  float* out = (float*)d_out;

  char* ws = (char*)d_ws;
  unsigned short* wT1 = (unsigned short*)(ws);                     // [3072][1024]
  unsigned short* wT2 = (unsigned short*)(ws + 6291456);           // [1024][1024]
  unsigned short* wT3 = (unsigned short*)(ws + 8388608);           // [4096][1024]
  unsigned short* wT4 = (unsigned short*)(ws + 16777216);          // [1024][4096]
  unsigned short* h   = (unsigned short*)(ws + 25165824);          // [4096][1024]
  unsigned short* qkv = (unsigned short*)(ws + 33554432);          // [4096][3072] / [4096][4096]
  unsigned short* yb  = (unsigned short*)(ws + 67108864);          // [4096][1024]

  hipFuncSetAttribute((const void*)gemm256_kernel<0>, hipFuncAttributeMaxDynamicSharedMemorySize, 131072);
  hipFuncSetAttribute((const void*)gemm256_kernel<2>, hipFuncAttributeMaxDynamicSharedMemorySize, 131072);
  hipFuncSetAttribute((const void*)gemm128_kernel, hipFuncAttributeMaxDynamicSharedMemorySize, 65536);

  transpose_bf16_kernel<<<dim3(3072 / 32, 1024 / 32), 256, 0, stream>>>(c_attn_w, wT1, 1024, 3072);
  transpose_bf16_kernel<<<dim3(1024 / 32, 1024 / 32), 256, 0, stream>>>(attn_proj_w, wT2, 1024, 1024);
  transpose_bf16_kernel<<<dim3(4096 / 32, 1024 / 32), 256, 0, stream>>>(fc_w, wT3, 1024, 4096);
  transpose_bf16_kernel<<<dim3(1024 / 32, 4096 / 32), 256, 0, stream>>>(mlp_proj_w, wT4, 4096, 1024);

  // LN1
  ln_kernel<<<Mrows, 256, 0, stream>>>(x, ln1_w, ln1_b, h);
  // qkv = h @ c_attn_w + b
  gemm256_kernel<0><<<(Mrows / 256) * (3072 / 256), 512, 131072, stream>>>(
      h, wT1, c_attn_b, qkv, Mrows, 3072, 1024, 3072 / 256);
  // attention -> y
  attn_kernel<<<1024, 256, 0, stream>>>(qkv, yb);
  // x1 = x + y @ attn_proj_w + b
  gemm128_kernel<<<(Mrows / 128) * (1024 / 128), 512, 65536, stream>>>(
      yb, wT2, attn_proj_b, x, out, Mrows, 1024, 1024, 1024 / 128);
  // LN2 on x1
  ln_kernel<<<Mrows, 256, 0, stream>>>(out, ln2_w, ln2_b, h);
  // a = gelu(h2 @ fc_w + b)
  gemm256_kernel<2><<<(Mrows / 256) * (4096 / 256), 512, 131072, stream>>>(
      h, wT3, fc_b, qkv, Mrows, 4096, 1024, 4096 / 256);
  // out = x1 + a @ mlp_proj_w + b
  gemm128_kernel<<<(Mrows / 128) * (1024 / 128), 512, 65536, stream>>>(
      qkv, wT4, mlp_proj_b, out, out, Mrows, 1024, 4096, 1024 / 128);
}

// Round 11
// 235.578 us; speedup vs baseline: 1.4946x; 1.0493x over previous
//
#include <hip/hip_runtime.h>
#include <hip/hip_bf16.h>

#define Bn 2
#define Tn 2048
#define Cn 1024
#define Hn 16
#define Dn 64
#define Mrows (Bn * Tn)   // 4096

typedef __attribute__((ext_vector_type(8))) short short8;
typedef __attribute__((ext_vector_type(4))) float f32x4;

typedef const __attribute__((address_space(1))) unsigned int* gas_ptr;
typedef __attribute__((address_space(3))) unsigned int* las_ptr;

__device__ __forceinline__ unsigned short f2b(float f) {
  unsigned int u = __builtin_bit_cast(unsigned int, f);
  return (unsigned short)((u + 0x7fffu + ((u >> 16) & 1u)) >> 16);
}

// ---------------- LayerNorm: f32 in -> bf16 out ----------------
__global__ __launch_bounds__(256) void ln_kernel(const float* __restrict__ x,
                                                 const float* __restrict__ w,
                                                 const float* __restrict__ b,
                                                 unsigned short* __restrict__ out) {
  const int row = blockIdx.x;
  const int t = threadIdx.x;
  const float4 v = *reinterpret_cast<const float4*>(x + (size_t)row * Cn + t * 4);
  float s = v.x + v.y + v.z + v.w;
  float s2 = v.x * v.x + v.y * v.y + v.z * v.z + v.w * v.w;
#pragma unroll
  for (int m = 1; m < 64; m <<= 1) { s += __shfl_xor(s, m); s2 += __shfl_xor(s2, m); }
  __shared__ float ls[4], ls2[4];
  if ((t & 63) == 0) { ls[t >> 6] = s; ls2[t >> 6] = s2; }
  __syncthreads();
  s  = ls[0] + ls[1] + ls[2] + ls[3];
  s2 = ls2[0] + ls2[1] + ls2[2] + ls2[3];
  const float mu = s * (1.0f / Cn);
  const float rstd = rsqrtf(s2 * (1.0f / Cn) - mu * mu + 1e-5f);
  const float4 wv = *reinterpret_cast<const float4*>(w + t * 4);
  const float4 bv = *reinterpret_cast<const float4*>(b + t * 4);
  unsigned short o[4];
  o[0] = f2b((v.x - mu) * rstd * wv.x + bv.x);
  o[1] = f2b((v.y - mu) * rstd * wv.y + bv.y);
  o[2] = f2b((v.z - mu) * rstd * wv.z + bv.z);
  o[3] = f2b((v.w - mu) * rstd * wv.w + bv.w);
  *reinterpret_cast<uint2*>(out + (size_t)row * Cn + t * 4) = *reinterpret_cast<uint2*>(o);
}

// ---------------- Transpose + f32->bf16: W[K][N] -> Wt[N][K] ----------------
__global__ __launch_bounds__(256) void transpose_bf16_kernel(const float* __restrict__ W,
                                                             unsigned short* __restrict__ Wt,
                                                             int K, int N) {
  __shared__ float tile[32][33];
  const int n0 = blockIdx.x * 32, k0 = blockIdx.y * 32;
  const int tx = threadIdx.x & 31, ty = threadIdx.x >> 5;  // ty 0..7
#pragma unroll
  for (int r = 0; r < 4; r++)
    tile[ty + r * 8][tx] = W[(size_t)(k0 + ty + r * 8) * N + n0 + tx];
  __syncthreads();
#pragma unroll
  for (int r = 0; r < 4; r++)
    Wt[(size_t)(n0 + ty + r * 8) * K + k0 + tx] = f2b(tile[tx][ty + r * 8]);
}

// ---------------- 256^2 8-wave deep-pipelined GEMM (m201-style) ----------------
// R11: T2 XOR swizzle f(row)=(row>>1)&3 on the [row][32] LDS tiles (rule #21:
// pre-swizzled GLOBAL source + linear LDS dest for gload_lds; matching XOR on
// the ds_read column). Breaks the 8-way quarter-wave bank conflict of 64B rows.
// Sync schedule identical to the R6-verified structure.
// EP=0: bf16 = v+bias; EP=2: bf16 = gelu(v+bias)
#define BUFS 16384
template <int EP>
__global__ __launch_bounds__(512, 2) void gemm256_kernel(
    const unsigned short* __restrict__ A, const unsigned short* __restrict__ Bt,
    const float* __restrict__ bias, void* out, int M, int N, int K, int nx) {
  extern __shared__ unsigned short lds[];
  const int tid = threadIdx.x;
  const int lane = tid & 63, w = tid >> 6;
  const int wm = w >> 2, wn = w & 3;
  const int l15 = lane & 15, l4 = lane >> 4;

  const int nwg = gridDim.x;
  int wg = blockIdx.x;
  wg = (wg & 7) * (nwg >> 3) + (wg >> 3);
  const int tile_m = (wg / nx) * 256;
  const int tile_n = (wg % nx) * 256;

  f32x4 acc[8][4] = {};

  // ---- invariant staging bases, PRE-SWIZZLED source column (chunk = r*4 + c16)
  const int ch0 = w * 64 + lane;                  // j=0 chunk 0..511
  const int r0 = ch0 >> 2;
  const int c0 = (((ch0 & 3) ^ ((r0 >> 1) & 3))) * 8;   // swizzled 16B chunk
  const unsigned short* gA0 = A + (size_t)(tile_m + r0) * K + c0;
  const unsigned short* gA1 = gA0 + (size_t)128 * K;    // row+128: f unchanged (128>>1 &3 == 0)
  const unsigned short* gB0 = Bt + (size_t)(tile_n + r0) * K + c0;
  const unsigned short* gB1 = gB0 + (size_t)128 * K;
  const int ldsA0 = (w * 64) * 8, ldsA1 = (512 + w * 64) * 8;

  auto stage = [&](unsigned short* Ab, int t) {
    unsigned short* Bb = Ab + 8192;
    const size_t ko = (size_t)t * 32;             // 32 ushorts = 64 B per K-tile
    __builtin_amdgcn_global_load_lds((gas_ptr)(gA0 + ko), (las_ptr)&Ab[ldsA0], 16, 0, 0);
    __builtin_amdgcn_global_load_lds((gas_ptr)(gA1 + ko), (las_ptr)&Ab[ldsA1], 16, 0, 0);
    __builtin_amdgcn_global_load_lds((gas_ptr)(gB0 + ko), (las_ptr)&Bb[ldsA0], 16, 0, 0);
    __builtin_amdgcn_global_load_lds((gas_ptr)(gB1 + ko), (las_ptr)&Bb[ldsA1], 16, 0, 0);
  };

  stage(lds, 0);
  stage(lds + BUFS, 1);
  stage(lds + 2 * BUFS, 2);
  asm volatile("s_waitcnt vmcnt(8)" ::: "memory");
  __builtin_amdgcn_s_barrier();
  __builtin_amdgcn_sched_barrier(0);

  // read-side swizzled column (per-lane invariant: f(row) = (l15>>1)&3)
  const int ca = (l4 ^ ((l15 >> 1) & 3)) * 8;

  const int nt = K >> 5;                          // multiple of 4 at all call sites
  for (int tb = 0; tb < nt; tb += 4) {
#pragma unroll
    for (int u = 0; u < 4; u++) {
      const int t = tb + u;                       // slot = t&3 = u (tb % 4 == 0)
      if (t + 3 < nt) stage(lds + (((u + 3) & 3) * BUFS), t + 3);
      __builtin_amdgcn_sched_barrier(0);

      const unsigned short* Ab = lds + u * BUFS;
      const unsigned short* Bb = Ab + 8192;
      short8 a[4], b[4];
#pragma unroll
      for (int i = 0; i < 4; i++) {
        a[i] = *reinterpret_cast<const short8*>(&Ab[(wm * 128 + i * 16 + l15) * 32 + ca]);
        b[i] = *reinterpret_cast<const short8*>(&Bb[(wn * 64 + i * 16 + l15) * 32 + ca]);
      }
      __builtin_amdgcn_s_barrier();
      asm volatile("s_waitcnt lgkmcnt(0)" ::: "memory");
      __builtin_amdgcn_sched_barrier(0);
      __builtin_amdgcn_s_setprio(1);
#pragma unroll
      for (int mi = 0; mi < 4; mi++)
#pragma unroll
        for (int ni = 0; ni < 4; ni++)
          acc[mi][ni] = __builtin_amdgcn_mfma_f32_16x16x32_bf16(a[mi], b[ni], acc[mi][ni], 0, 0, 0);
      __builtin_amdgcn_s_setprio(0);
      __builtin_amdgcn_sched_barrier(0);
      __builtin_amdgcn_s_barrier();

#pragma unroll
      for (int i = 0; i < 4; i++)
        a[i] = *reinterpret_cast<const short8*>(&Ab[(wm * 128 + 64 + i * 16 + l15) * 32 + ca]);
      asm volatile("s_waitcnt lgkmcnt(0)" ::: "memory");
      __builtin_amdgcn_sched_barrier(0);
      __builtin_amdgcn_s_setprio(1);
#pragma unroll
      for (int mi = 0; mi < 4; mi++)
#pragma unroll
        for (int ni = 0; ni < 4; ni++)
          acc[mi + 4][ni] = __builtin_amdgcn_mfma_f32_16x16x32_bf16(a[mi], b[ni], acc[mi + 4][ni], 0, 0, 0);
      __builtin_amdgcn_s_setprio(0);
      __builtin_amdgcn_sched_barrier(0);

      if (t + 3 < nt) {
        asm volatile("s_waitcnt vmcnt(8)" ::: "memory");
      } else if (t + 2 < nt) {
        asm volatile("s_waitcnt vmcnt(4)" ::: "memory");
      } else if (t + 1 < nt) {
        asm volatile("s_waitcnt vmcnt(0)" ::: "memory");
      }
      __builtin_amdgcn_s_barrier();
      __builtin_amdgcn_sched_barrier(0);
    }
  }

#pragma unroll
  for (int ni = 0; ni < 4; ni++) {
    const int col = tile_n + wn * 64 + ni * 16 + l15;
    const float bv = bias[col];
#pragma unroll
    for (int mi = 0; mi < 8; mi++) {
#pragma unroll
      for (int r = 0; r < 4; r++) {
        const int row = tile_m + wm * 128 + mi * 16 + l4 * 4 + r;
        const size_t idx = (size_t)row * N + col;
        float v = acc[mi][ni][r] + bv;
        if (EP == 0) {
          ((unsigned short*)out)[idx] = f2b(v);
        } else {
          float g = 0.5f * v * (1.0f + erff(v * 0.70710678118f));
          ((unsigned short*)out)[idx] = f2b(g);
        }
      }
    }
  }
}

// ---------------- 128^2 8-wave deep-pipelined GEMM (no split-K) ----------------
// Same R11 swizzle. EP: f32 out = v + bias + res (res may alias out:
// read-once-then-written-once per idx by one thread).
__global__ __launch_bounds__(512, 2) void gemm128_kernel(
    const unsigned short* __restrict__ A, const unsigned short* __restrict__ Bt,
    const float* __restrict__ bias, const float* __restrict__ res, float* __restrict__ out,
    int M, int N, int K, int nx) {
  extern __shared__ unsigned short lds[];
  const int tid = threadIdx.x;
  const int lane = tid & 63, w = tid >> 6;
  const int wm = w >> 2, wn = w & 3;
  const int l15 = lane & 15, l4 = lane >> 4;

  const int nwg = gridDim.x;
  int wg = blockIdx.x;
  wg = (wg & 7) * (nwg >> 3) + (wg >> 3);
  const int tile_m = (wg / nx) * 128;
  const int tile_n = (wg % nx) * 128;

  f32x4 acc[4][2] = {};

  // waves 0-3 stage A, 4-7 stage B; 2 chunks per thread per tile; swizzled source.
  const unsigned short* Gs = (w < 4) ? A : Bt;
  const int tb0 = (w < 4) ? tile_m : tile_n;
  const int ch0 = (w & 3) * 128 + lane;           // j=0 chunk
  const int r0c = ch0 >> 2;
  const int c0s = (((ch0 & 3) ^ ((r0c >> 1) & 3))) * 8;
  const unsigned short* g0 = Gs + (size_t)(tb0 + r0c) * K + c0s;
  const unsigned short* g1 = g0 + (size_t)16 * K;  // chunk+64 -> row+16: f unchanged
  const int lds0 = ((w & 3) * 128) * 8, lds1 = ((w & 3) * 128 + 64) * 8;
  const int half = (w < 4) ? 0 : 4096;

  auto stage = [&](unsigned short* slot, int t) {
    unsigned short* Lb = slot + half;
    const size_t ko = (size_t)t * 32;
    __builtin_amdgcn_global_load_lds((gas_ptr)(g0 + ko), (las_ptr)&Lb[lds0], 16, 0, 0);
    __builtin_amdgcn_global_load_lds((gas_ptr)(g1 + ko), (las_ptr)&Lb[lds1], 16, 0, 0);
  };

  stage(lds, 0);
  stage(lds + 8192, 1);
  stage(lds + 16384, 2);
  asm volatile("s_waitcnt vmcnt(4)" ::: "memory");
  __builtin_amdgcn_s_barrier();
  __builtin_amdgcn_sched_barrier(0);

  const int ca = (l4 ^ ((l15 >> 1) & 3)) * 8;

  const int nt = K >> 5;                          // 32 or 128
  for (int tb = 0; tb < nt; tb += 4) {
#pragma unroll
    for (int u = 0; u < 4; u++) {
      const int t = tb + u;
      if (t + 3 < nt) stage(lds + ((u + 3) & 3) * 8192, t + 3);
      __builtin_amdgcn_sched_barrier(0);

      const unsigned short* Ab = lds + u * 8192;
      const unsigned short* Bb = Ab + 4096;
      short8 a[2], b[2];
#pragma unroll
      for (int i = 0; i < 2; i++) {
        a[i] = *reinterpret_cast<const short8*>(&Ab[(wm * 64 + i * 16 + l15) * 32 + ca]);
        b[i] = *reinterpret_cast<const short8*>(&Bb[(wn * 32 + i * 16 + l15) * 32 + ca]);
      }
      __builtin_amdgcn_s_barrier();
      asm volatile("s_waitcnt lgkmcnt(0)" ::: "memory");
      __builtin_amdgcn_sched_barrier(0);
      __builtin_amdgcn_s_setprio(1);
#pragma unroll
      for (int mi = 0; mi < 2; mi++)
#pragma unroll
        for (int ni = 0; ni < 2; ni++)
          acc[mi][ni] = __builtin_amdgcn_mfma_f32_16x16x32_bf16(a[mi], b[ni], acc[mi][ni], 0, 0, 0);
      __builtin_amdgcn_s_setprio(0);
      __builtin_amdgcn_sched_barrier(0);
      __builtin_amdgcn_s_barrier();

#pragma unroll
      for (int i = 0; i < 2; i++)
        a[i] = *reinterpret_cast<const short8*>(&Ab[(wm * 64 + 32 + i * 16 + l15) * 32 + ca]);
      asm volatile("s_waitcnt lgkmcnt(0)" ::: "memory");
      __builtin_amdgcn_sched_barrier(0);
      __builtin_amdgcn_s_setprio(1);
#pragma unroll
      for (int mi = 0; mi < 2; mi++)
#pragma unroll
        for (int ni = 0; ni < 2; ni++)
          acc[mi + 2][ni] = __builtin_amdgcn_mfma_f32_16x16x32_bf16(a[mi], b[ni], acc[mi + 2][ni], 0, 0, 0);
      __builtin_amdgcn_s_setprio(0);
      __builtin_amdgcn_sched_barrier(0);

      if (t + 3 < nt) {
        asm volatile("s_waitcnt vmcnt(4)" ::: "memory");
      } else if (t + 2 < nt) {
        asm volatile("s_waitcnt vmcnt(2)" ::: "memory");
      } else if (t + 1 < nt) {
        asm volatile("s_waitcnt vmcnt(0)" ::: "memory");
      }
      __builtin_amdgcn_s_barrier();
      __builtin_amdgcn_sched_barrier(0);
    }
  }

#pragma unroll
  for (int ni = 0; ni < 2; ni++) {
    const int col = tile_n + wn * 32 + ni * 16 + l15;
    const float bv = bias[col];
#pragma unroll
    for (int mi = 0; mi < 4; mi++) {
#pragma unroll
      for (int r = 0; r < 4; r++) {
        const int row = tile_m + wm * 64 + mi * 16 + l4 * 4 + r;
        const size_t idx = (size_t)row * N + col;
        out[idx] = acc[mi][ni][r] + bv + res[idx];
      }
    }
  }
}

// ---------------- Strided-sparse flash attention v3 (unchanged from R9) ----------------
__global__ __launch_bounds__(256, 4) void attn_kernel(const unsigned short* __restrict__ qkv,
                                                      unsigned short* __restrict__ y) {
  __shared__ unsigned short SH[17408];   // 34816 B
  const int tid = threadIdx.x;
  const int lane = tid & 63, w = tid >> 6;
  const int l15 = lane & 15, l4 = lane >> 4;

  const int bi = blockIdx.x;
  const int quarter = bi >> 8, rest = bi & 255;
  const int bh = rest >> 3, sub = rest & 7;
  int qt;
  if (quarter == 0) qt = sub;
  else if (quarter == 1) qt = 15 - sub;
  else if (quarter == 2) qt = 16 + sub;
  else qt = 31 - sub;
  const int bb = bh >> 4, hh = bh & 15;
  const int q0 = qt * 64;
  const size_t base = (size_t)bb * Tn * (3 * Cn) + hh * 64;

  const int nfar = qt >> 1;
  const int ntiles = nfar + (q0 ? 2 : 1);

  unsigned short* Vt = SH + 8192;
  unsigned short* Ps = SH + 12800 + w * 1152;

  auto keyof = [&](int t, int row) -> int {
    if (t < nfar) return t * 128 + 2 * row;
    return q0 - 64 * (ntiles - 1 - t) + row;
  };
  auto stageK = [&](int t) {
    unsigned short* kb = SH + ((t & 1) << 12);
#pragma unroll
    for (int u = 0; u < 2; u++) {
      const int chunk = u * 256 + tid;
      const int row = chunk >> 3, cc = chunk & 7;
      const int csrc = cc ^ (row & 7);
      const int key = keyof(t, row);
      __builtin_amdgcn_global_load_lds(
          (gas_ptr)&qkv[base + Cn + (size_t)key * (3 * Cn) + csrc * 8],
          (las_ptr)&kb[(u * 256 + (w << 6)) * 8], 16, 0, 0);
    }
  };
  uint4 vr[2];
  auto fetchV = [&](int t) {
#pragma unroll
    for (int u = 0; u < 2; u++) {
      const int chunk = u * 256 + tid;
      const int row = chunk >> 3, cc = chunk & 7;
      const int key = keyof(t, row);
      vr[u] = *reinterpret_cast<const uint4*>(&qkv[base + 2 * Cn + (size_t)key * (3 * Cn) + cc * 8]);
    }
  };

#pragma unroll
  for (int u = 0; u < 2; u++) {
    const int chunk = u * 256 + tid;
    const int row = chunk >> 3, cc = chunk & 7;
    const int csrc = cc ^ (row & 7);
    __builtin_amdgcn_global_load_lds(
        (gas_ptr)&qkv[base + (size_t)(q0 + row) * (3 * Cn) + csrc * 8],
        (las_ptr)&SH[(u * 256 + (w << 6)) * 8], 16, 0, 0);
  }
  __syncthreads();
  short8 qf[2];
#pragma unroll
  for (int ks = 0; ks < 2; ks++) {
    const int r = (w << 4) + l15;
    qf[ks] = *reinterpret_cast<const short8*>(&SH[r * 64 + (((ks * 4 + l4) ^ (l15 & 7)) * 8)]);
  }
  asm volatile("s_waitcnt lgkmcnt(0)" ::: "memory");
  __builtin_amdgcn_s_barrier();
  __builtin_amdgcn_sched_barrier(0);
  stageK(0);
  fetchV(0);
  __syncthreads();

  f32x4 acc_o[4] = {};
  float mrow[4], lrow[4];
#pragma unroll
  for (int r = 0; r < 4; r++) { mrow[r] = -1e30f; lrow[r] = 0.0f; }

  for (int t = 0; t < ntiles; ++t) {
#pragma unroll
    for (int u = 0; u < 2; u++) {
      const int chunk = u * 256 + tid;
      const int row = chunk >> 3, cc = chunk & 7;
      unsigned short tmp[8];
      *reinterpret_cast<uint4*>(tmp) = vr[u];
      const int xr = row ^ (cc << 3);
#pragma unroll
      for (int j = 0; j < 8; j++) Vt[(cc * 8 + j) * 72 + xr] = tmp[j];
    }
    if (t + 1 < ntiles) { stageK(t + 1); fetchV(t + 1); }
    asm volatile("s_waitcnt lgkmcnt(0)" ::: "memory");
    __builtin_amdgcn_s_barrier();
    __builtin_amdgcn_sched_barrier(0);

    const unsigned short* Kb = SH + ((t & 1) << 12);
    f32x4 s[4] = {};
#pragma unroll
    for (int ni = 0; ni < 4; ni++) {
#pragma unroll
      for (int ks = 0; ks < 2; ks++) {
        const int r = ni * 16 + l15;
        short8 kf = *reinterpret_cast<const short8*>(&Kb[r * 64 + (((ks * 4 + l4) ^ (l15 & 7)) * 8)]);
        s[ni] = __builtin_amdgcn_mfma_f32_16x16x32_bf16(qf[ks], kf, s[ni], 0, 0, 0);
      }
    }

    const bool far = (t < nfar);
    const int kb0 = far ? t * 128 : q0 - 64 * (ntiles - 1 - t);
#pragma unroll
    for (int ni = 0; ni < 4; ni++) {
      const int pos = ni * 16 + l15;
      const int j = far ? kb0 + 2 * pos : kb0 + pos;
#pragma unroll
      for (int r = 0; r < 4; r++) {
        float v = s[ni][r] * 0.125f;
        if (far) {
          v = (j < q0 - 64) ? v : -1e30f;
        } else {
          const int iq = q0 + (w << 4) + l4 * 4 + r;
          const bool ok = (j <= iq) && ((j >= iq - 4) || ((j & 1) == 0));
          v = ok ? v : -1e30f;
        }
        s[ni][r] = v;
      }
    }

#pragma unroll
    for (int r = 0; r < 4; r++) {
      float tm = fmaxf(fmaxf(s[0][r], s[1][r]), fmaxf(s[2][r], s[3][r]));
      tm = fmaxf(tm, __shfl_xor(tm, 1));
      tm = fmaxf(tm, __shfl_xor(tm, 2));
      tm = fmaxf(tm, __shfl_xor(tm, 4));
      tm = fmaxf(tm, __shfl_xor(tm, 8));
      const float mnew = fmaxf(mrow[r], tm);
      const float alpha = __expf(mrow[r] - mnew);
      mrow[r] = mnew;
      lrow[r] *= alpha;
#pragma unroll
      for (int nd = 0; nd < 4; nd++) acc_o[nd][r] *= alpha;
      float rs = 0.0f;
#pragma unroll
      for (int ni = 0; ni < 4; ni++) {
        const float pv = __expf(s[ni][r] - mnew);
        s[ni][r] = pv;
        rs += pv;
      }
      rs += __shfl_xor(rs, 1); rs += __shfl_xor(rs, 2);
      rs += __shfl_xor(rs, 4); rs += __shfl_xor(rs, 8);
      lrow[r] += rs;
    }

#pragma unroll
    for (int ni = 0; ni < 4; ni++)
#pragma unroll
      for (int r = 0; r < 4; r++)
        Ps[(l4 * 4 + r) * 72 + ni * 16 + l15] = f2b(s[ni][r]);

#pragma unroll
    for (int kss = 0; kss < 2; kss++) {
      short8 pf = *reinterpret_cast<const short8*>(&Ps[l15 * 72 + kss * 32 + l4 * 8]);
#pragma unroll
      for (int nd = 0; nd < 4; nd++) {
        const int d = nd * 16 + l15;
        const int kcol = (kss * 32 + l4 * 8) ^ ((d >> 3) << 3);
        short8 vf = *reinterpret_cast<const short8*>(&Vt[d * 72 + kcol]);
        acc_o[nd] = __builtin_amdgcn_mfma_f32_16x16x32_bf16(pf, vf, acc_o[nd], 0, 0, 0);
      }
    }

    __syncthreads();
  }

#pragma unroll
  for (int r = 0; r < 4; r++) {
    const float inv = 1.0f / lrow[r];
    const int row = q0 + (w << 4) + l4 * 4 + r;
#pragma unroll
    for (int nd = 0; nd < 4; nd++) {
      const int col = nd * 16 + l15;
      y[((size_t)bb * Tn + row) * Cn + hh * 64 + col] = f2b(acc_o[nd][r] * inv);
    }
  }
}

// ---------------- launch ----------------
extern "C" void kernel_launch(void* const* d_in, const int* in_sizes, int n_in,
                              void* d_out, int out_size, void* d_ws, size_t ws_size,
                              hipStream_t stream) {
  const float* x           = (const float*)d_in[0];
  const float* ln1_w       = (const float*)d_in[1];
  const float* ln1_b       = (const float*)d_in[2];
  const float* c_attn_w    = (const float*)d_in[3];
  const float* c_attn_b    = (const float*)d_in[4];
  const float* attn_proj_w = (const float*)d_in[5];
  const float* attn_proj_b = (const float*)d_in[6];
  const float* ln2_w       = (const float*)d_in[7];
  const float* ln2_b       = (const float*)d_in[8];
  const float* fc_w        = (const float*)d_in[9];
  const float* fc_b        = (const float*)d_in[10];
  const float* mlp_proj_w  = (const float*)d_in[11];
  const float* mlp_proj_b  = (const float*)d_in[12];
  float* out = (float*)d_out;

  char* ws = (char*)d_ws;
  unsigned short* wT1 = (unsigned short*)(ws);                     // [3072][1024]
  unsigned short* wT2 = (unsigned short*)(ws + 6291456);           // [1024][1024]
  unsigned short* wT3 = (unsigned short*)(ws + 8388608);           // [4096][1024]
  unsigned short* wT4 = (unsigned short*)(ws + 16777216);          // [1024][4096]
  unsigned short* h   = (unsigned short*)(ws + 25165824);          // [4096][1024]
  unsigned short* qkv = (unsigned short*)(ws + 33554432);          // [4096][3072] / [4096][4096]
  unsigned short* yb  = (unsigned short*)(ws + 67108864);          // [4096][1024]

  hipFuncSetAttribute((const void*)gemm256_kernel<0>, hipFuncAttributeMaxDynamicSharedMemorySize, 131072);
  hipFuncSetAttribute((const void*)gemm256_kernel<2>, hipFuncAttributeMaxDynamicSharedMemorySize, 131072);
  hipFuncSetAttribute((const void*)gemm128_kernel, hipFuncAttributeMaxDynamicSharedMemorySize, 65536);

  transpose_bf16_kernel<<<dim3(3072 / 32, 1024 / 32), 256, 0, stream>>>(c_attn_w, wT1, 1024, 3072);
  transpose_bf16_kernel<<<dim3(1024 / 32, 1024 / 32), 256, 0, stream>>>(attn_proj_w, wT2, 1024, 1024);
  transpose_bf16_kernel<<<dim3(4096 / 32, 1024 / 32), 256, 0, stream>>>(fc_w, wT3, 1024, 4096);
  transpose_bf16_kernel<<<dim3(1024 / 32, 4096 / 32), 256, 0, stream>>>(mlp_proj_w, wT4, 4096, 1024);

  // LN1
  ln_kernel<<<Mrows, 256, 0, stream>>>(x, ln1_w, ln1_b, h);
  // qkv = h @ c_attn_w + b
  gemm256_kernel<0><<<(Mrows / 256) * (3072 / 256), 512, 131072, stream>>>(
      h, wT1, c_attn_b, qkv, Mrows, 3072, 1024, 3072 / 256);
  // attention -> y
  attn_kernel<<<1024, 256, 0, stream>>>(qkv, yb);
  // x1 = x + y @ attn_proj_w + b
  gemm128_kernel<<<(Mrows / 128) * (1024 / 128), 512, 65536, stream>>>(
      yb, wT2, attn_proj_b, x, out, Mrows, 1024, 1024, 1024 / 128);
  // LN2 on x1
  ln_kernel<<<Mrows, 256, 0, stream>>>(out, ln2_w, ln2_b, h);
  // a = gelu(h2 @ fc_w + b)
  gemm256_kernel<2><<<(Mrows / 256) * (4096 / 256), 512, 131072, stream>>>(
      h, wT3, fc_b, qkv, Mrows, 4096, 1024, 4096 / 256);
  // out = x1 + a @ mlp_proj_w + b
  gemm128_kernel<<<(Mrows / 128) * (1024 / 128), 512, 65536, stream>>>(
      qkv, wT4, mlp_proj_b, out, out, Mrows, 1024, 4096, 1024 / 128);
}

// Round 12
// 228.656 us; speedup vs baseline: 1.5398x; 1.0303x over previous
//
#include <hip/hip_runtime.h>
#include <hip/hip_bf16.h>

#define Bn 2
#define Tn 2048
#define Cn 1024
#define Hn 16
#define Dn 64
#define Mrows (Bn * Tn)   // 4096

typedef __attribute__((ext_vector_type(8))) short short8;
typedef __attribute__((ext_vector_type(4))) float f32x4;

typedef const __attribute__((address_space(1))) unsigned int* gas_ptr;
typedef __attribute__((address_space(3))) unsigned int* las_ptr;

__device__ __forceinline__ unsigned short f2b(float f) {
  unsigned int u = __builtin_bit_cast(unsigned int, f);
  return (unsigned short)((u + 0x7fffu + ((u >> 16) & 1u)) >> 16);
}

__device__ __forceinline__ float gelu_f(float v) {
  // tanh-form GELU via hardware exp; |delta vs erf form| <= ~5e-4 (threshold 0.126)
  float u2 = v + 0.044715f * v * v * v;
  float e = __expf(1.5957691216f * u2);
  float th = 1.0f - 2.0f / (e + 1.0f);
  return 0.5f * v * (1.0f + th);
}

// ---------------- LayerNorm: f32 in -> bf16 out ----------------
__global__ __launch_bounds__(256) void ln_kernel(const float* __restrict__ x,
                                                 const float* __restrict__ w,
                                                 const float* __restrict__ b,
                                                 unsigned short* __restrict__ out) {
  const int row = blockIdx.x;
  const int t = threadIdx.x;
  const float4 v = *reinterpret_cast<const float4*>(x + (size_t)row * Cn + t * 4);
  float s = v.x + v.y + v.z + v.w;
  float s2 = v.x * v.x + v.y * v.y + v.z * v.z + v.w * v.w;
#pragma unroll
  for (int m = 1; m < 64; m <<= 1) { s += __shfl_xor(s, m); s2 += __shfl_xor(s2, m); }
  __shared__ float ls[4], ls2[4];
  if ((t & 63) == 0) { ls[t >> 6] = s; ls2[t >> 6] = s2; }
  __syncthreads();
  s  = ls[0] + ls[1] + ls[2] + ls[3];
  s2 = ls2[0] + ls2[1] + ls2[2] + ls2[3];
  const float mu = s * (1.0f / Cn);
  const float rstd = rsqrtf(s2 * (1.0f / Cn) - mu * mu + 1e-5f);
  const float4 wv = *reinterpret_cast<const float4*>(w + t * 4);
  const float4 bv = *reinterpret_cast<const float4*>(b + t * 4);
  unsigned short o[4];
  o[0] = f2b((v.x - mu) * rstd * wv.x + bv.x);
  o[1] = f2b((v.y - mu) * rstd * wv.y + bv.y);
  o[2] = f2b((v.z - mu) * rstd * wv.z + bv.z);
  o[3] = f2b((v.w - mu) * rstd * wv.w + bv.w);
  *reinterpret_cast<uint2*>(out + (size_t)row * Cn + t * 4) = *reinterpret_cast<uint2*>(o);
}

// ---------------- Transpose + f32->bf16: W[K][N] -> Wt[N][K] ----------------
__global__ __launch_bounds__(256) void transpose_bf16_kernel(const float* __restrict__ W,
                                                             unsigned short* __restrict__ Wt,
                                                             int K, int N) {
  __shared__ float tile[32][33];
  const int n0 = blockIdx.x * 32, k0 = blockIdx.y * 32;
  const int tx = threadIdx.x & 31, ty = threadIdx.x >> 5;  // ty 0..7
#pragma unroll
  for (int r = 0; r < 4; r++)
    tile[ty + r * 8][tx] = W[(size_t)(k0 + ty + r * 8) * N + n0 + tx];
  __syncthreads();
#pragma unroll
  for (int r = 0; r < 4; r++)
    Wt[(size_t)(n0 + ty + r * 8) * K + k0 + tx] = f2b(tile[tx][ty + r * 8]);
}

// ---------------- 256^2 8-wave pipelined GEMM — R12 slim-sync ----------------
// ONE barrier + ONE counted vmcnt per K-tile (hazard proof):
//  (a) read buf[t&3]: trailing vmcnt(8)@iter t-1 leaves only tiles t+1,t+2 in
//      flight => tile t landed; barrier publishes to all waves.
//  (b) stage(t+3) overwrites buf[(t-1)&3]; its last reads completed before
//      iter t-1's lgkmcnt(0)->MFMA->barrier => WAR safe.
// All 12 ds_reads issued up front; order pinned (a,b | a2) via sched_barrier;
// counted lgkmcnt(4) lets phase-A MFMA overlap phase-B fragment reads.
// EP=0: bf16 = v+bias; EP=2: bf16 = gelu(v+bias)
#define BUFS 16384
template <int EP>
__global__ __launch_bounds__(512, 2) void gemm256_kernel(
    const unsigned short* __restrict__ A, const unsigned short* __restrict__ Bt,
    const float* __restrict__ bias, void* out, int M, int N, int K, int nx) {
  extern __shared__ unsigned short lds[];
  const int tid = threadIdx.x;
  const int lane = tid & 63, w = tid >> 6;
  const int wm = w >> 2, wn = w & 3;
  const int l15 = lane & 15, l4 = lane >> 4;

  const int nwg = gridDim.x;
  int wg = blockIdx.x;
  wg = (wg & 7) * (nwg >> 3) + (wg >> 3);
  const int tile_m = (wg / nx) * 256;
  const int tile_n = (wg % nx) * 256;

  f32x4 acc[8][4] = {};

  // invariant staging bases, PRE-SWIZZLED source column (T2, rule #21)
  const int ch0 = w * 64 + lane;
  const int r0 = ch0 >> 2;
  const int c0 = (((ch0 & 3) ^ ((r0 >> 1) & 3))) * 8;
  const unsigned short* gA0 = A + (size_t)(tile_m + r0) * K + c0;
  const unsigned short* gA1 = gA0 + (size_t)128 * K;
  const unsigned short* gB0 = Bt + (size_t)(tile_n + r0) * K + c0;
  const unsigned short* gB1 = gB0 + (size_t)128 * K;
  const int ldsA0 = (w * 64) * 8, ldsA1 = (512 + w * 64) * 8;

  auto stage = [&](unsigned short* Ab, int t) {
    unsigned short* Bb = Ab + 8192;
    const size_t ko = (size_t)t * 32;
    __builtin_amdgcn_global_load_lds((gas_ptr)(gA0 + ko), (las_ptr)&Ab[ldsA0], 16, 0, 0);
    __builtin_amdgcn_global_load_lds((gas_ptr)(gA1 + ko), (las_ptr)&Ab[ldsA1], 16, 0, 0);
    __builtin_amdgcn_global_load_lds((gas_ptr)(gB0 + ko), (las_ptr)&Bb[ldsA0], 16, 0, 0);
    __builtin_amdgcn_global_load_lds((gas_ptr)(gB1 + ko), (las_ptr)&Bb[ldsA1], 16, 0, 0);
  };

  stage(lds, 0);
  stage(lds + BUFS, 1);
  stage(lds + 2 * BUFS, 2);
  asm volatile("s_waitcnt vmcnt(8)" ::: "memory");
  __builtin_amdgcn_s_barrier();
  __builtin_amdgcn_sched_barrier(0);

  const int ca = (l4 ^ ((l15 >> 1) & 3)) * 8;   // read-side swizzled column

  const int nt = K >> 5;
  for (int tb = 0; tb < nt; tb += 4) {
#pragma unroll
    for (int u = 0; u < 4; u++) {
      const int t = tb + u;
      if (t + 3 < nt) stage(lds + (((u + 3) & 3) * BUFS), t + 3);

      const unsigned short* Ab = lds + u * BUFS;
      const unsigned short* Bb = Ab + 8192;
      short8 a[4], b[4], a2[4];
#pragma unroll
      for (int i = 0; i < 4; i++) {
        a[i] = *reinterpret_cast<const short8*>(&Ab[(wm * 128 + i * 16 + l15) * 32 + ca]);
        b[i] = *reinterpret_cast<const short8*>(&Bb[(wn * 64 + i * 16 + l15) * 32 + ca]);
      }
      __builtin_amdgcn_sched_barrier(0);          // pin: a,b issued before a2
#pragma unroll
      for (int i = 0; i < 4; i++)
        a2[i] = *reinterpret_cast<const short8*>(&Ab[(wm * 128 + 64 + i * 16 + l15) * 32 + ca]);

      asm volatile("s_waitcnt lgkmcnt(4)" ::: "memory");   // a,b ready (in-order DS)
      __builtin_amdgcn_sched_barrier(0);
      __builtin_amdgcn_s_setprio(1);
#pragma unroll
      for (int mi = 0; mi < 4; mi++)
#pragma unroll
        for (int ni = 0; ni < 4; ni++)
          acc[mi][ni] = __builtin_amdgcn_mfma_f32_16x16x32_bf16(a[mi], b[ni], acc[mi][ni], 0, 0, 0);
      __builtin_amdgcn_s_setprio(0);
      __builtin_amdgcn_sched_barrier(0);

      asm volatile("s_waitcnt lgkmcnt(0)" ::: "memory");   // a2 ready
      __builtin_amdgcn_sched_barrier(0);
      __builtin_amdgcn_s_setprio(1);
#pragma unroll
      for (int mi = 0; mi < 4; mi++)
#pragma unroll
        for (int ni = 0; ni < 4; ni++)
          acc[mi + 4][ni] = __builtin_amdgcn_mfma_f32_16x16x32_bf16(a2[mi], b[ni], acc[mi + 4][ni], 0, 0, 0);
      __builtin_amdgcn_s_setprio(0);
      __builtin_amdgcn_sched_barrier(0);

      if (t + 3 < nt) {
        asm volatile("s_waitcnt vmcnt(8)" ::: "memory");
      } else if (t + 2 < nt) {
        asm volatile("s_waitcnt vmcnt(4)" ::: "memory");
      } else if (t + 1 < nt) {
        asm volatile("s_waitcnt vmcnt(0)" ::: "memory");
      }
      __builtin_amdgcn_s_barrier();               // the single per-iter barrier
      __builtin_amdgcn_sched_barrier(0);
    }
  }

#pragma unroll
  for (int ni = 0; ni < 4; ni++) {
    const int col = tile_n + wn * 64 + ni * 16 + l15;
    const float bv = bias[col];
#pragma unroll
    for (int mi = 0; mi < 8; mi++) {
#pragma unroll
      for (int r = 0; r < 4; r++) {
        const int row = tile_m + wm * 128 + mi * 16 + l4 * 4 + r;
        const size_t idx = (size_t)row * N + col;
        float v = acc[mi][ni][r] + bv;
        if (EP == 0) {
          ((unsigned short*)out)[idx] = f2b(v);
        } else {
          ((unsigned short*)out)[idx] = f2b(gelu_f(v));
        }
      }
    }
  }
}

// ---------------- 128^2 8-wave pipelined GEMM — R12 slim-sync ----------------
// Same single-barrier proof with 2 loads/wave/tile (counts halved).
// EP: f32 out = v + bias + res (res may alias out: read-once-write-once per idx).
__global__ __launch_bounds__(512, 2) void gemm128_kernel(
    const unsigned short* __restrict__ A, const unsigned short* __restrict__ Bt,
    const float* __restrict__ bias, const float* __restrict__ res, float* __restrict__ out,
    int M, int N, int K, int nx) {
  extern __shared__ unsigned short lds[];
  const int tid = threadIdx.x;
  const int lane = tid & 63, w = tid >> 6;
  const int wm = w >> 2, wn = w & 3;
  const int l15 = lane & 15, l4 = lane >> 4;

  const int nwg = gridDim.x;
  int wg = blockIdx.x;
  wg = (wg & 7) * (nwg >> 3) + (wg >> 3);
  const int tile_m = (wg / nx) * 128;
  const int tile_n = (wg % nx) * 128;

  f32x4 acc[4][2] = {};

  const unsigned short* Gs = (w < 4) ? A : Bt;
  const int tb0 = (w < 4) ? tile_m : tile_n;
  const int ch0 = (w & 3) * 128 + lane;
  const int r0c = ch0 >> 2;
  const int c0s = (((ch0 & 3) ^ ((r0c >> 1) & 3))) * 8;
  const unsigned short* g0 = Gs + (size_t)(tb0 + r0c) * K + c0s;
  const unsigned short* g1 = g0 + (size_t)16 * K;
  const int lds0 = ((w & 3) * 128) * 8, lds1 = ((w & 3) * 128 + 64) * 8;
  const int half = (w < 4) ? 0 : 4096;

  auto stage = [&](unsigned short* slot, int t) {
    unsigned short* Lb = slot + half;
    const size_t ko = (size_t)t * 32;
    __builtin_amdgcn_global_load_lds((gas_ptr)(g0 + ko), (las_ptr)&Lb[lds0], 16, 0, 0);
    __builtin_amdgcn_global_load_lds((gas_ptr)(g1 + ko), (las_ptr)&Lb[lds1], 16, 0, 0);
  };

  stage(lds, 0);
  stage(lds + 8192, 1);
  stage(lds + 16384, 2);
  asm volatile("s_waitcnt vmcnt(4)" ::: "memory");
  __builtin_amdgcn_s_barrier();
  __builtin_amdgcn_sched_barrier(0);

  const int ca = (l4 ^ ((l15 >> 1) & 3)) * 8;

  const int nt = K >> 5;
  for (int tb = 0; tb < nt; tb += 4) {
#pragma unroll
    for (int u = 0; u < 4; u++) {
      const int t = tb + u;
      if (t + 3 < nt) stage(lds + ((u + 3) & 3) * 8192, t + 3);

      const unsigned short* Ab = lds + u * 8192;
      const unsigned short* Bb = Ab + 4096;
      short8 a[2], b[2], a2[2];
#pragma unroll
      for (int i = 0; i < 2; i++) {
        a[i] = *reinterpret_cast<const short8*>(&Ab[(wm * 64 + i * 16 + l15) * 32 + ca]);
        b[i] = *reinterpret_cast<const short8*>(&Bb[(wn * 32 + i * 16 + l15) * 32 + ca]);
      }
      __builtin_amdgcn_sched_barrier(0);
#pragma unroll
      for (int i = 0; i < 2; i++)
        a2[i] = *reinterpret_cast<const short8*>(&Ab[(wm * 64 + 32 + i * 16 + l15) * 32 + ca]);

      asm volatile("s_waitcnt lgkmcnt(2)" ::: "memory");
      __builtin_amdgcn_sched_barrier(0);
      __builtin_amdgcn_s_setprio(1);
#pragma unroll
      for (int mi = 0; mi < 2; mi++)
#pragma unroll
        for (int ni = 0; ni < 2; ni++)
          acc[mi][ni] = __builtin_amdgcn_mfma_f32_16x16x32_bf16(a[mi], b[ni], acc[mi][ni], 0, 0, 0);
      __builtin_amdgcn_s_setprio(0);
      __builtin_amdgcn_sched_barrier(0);

      asm volatile("s_waitcnt lgkmcnt(0)" ::: "memory");
      __builtin_amdgcn_sched_barrier(0);
      __builtin_amdgcn_s_setprio(1);
#pragma unroll
      for (int mi = 0; mi < 2; mi++)
#pragma unroll
        for (int ni = 0; ni < 2; ni++)
          acc[mi + 2][ni] = __builtin_amdgcn_mfma_f32_16x16x32_bf16(a2[mi], b[ni], acc[mi + 2][ni], 0, 0, 0);
      __builtin_amdgcn_s_setprio(0);
      __builtin_amdgcn_sched_barrier(0);

      if (t + 3 < nt) {
        asm volatile("s_waitcnt vmcnt(4)" ::: "memory");
      } else if (t + 2 < nt) {
        asm volatile("s_waitcnt vmcnt(2)" ::: "memory");
      } else if (t + 1 < nt) {
        asm volatile("s_waitcnt vmcnt(0)" ::: "memory");
      }
      __builtin_amdgcn_s_barrier();
      __builtin_amdgcn_sched_barrier(0);
    }
  }

#pragma unroll
  for (int ni = 0; ni < 2; ni++) {
    const int col = tile_n + wn * 32 + ni * 16 + l15;
    const float bv = bias[col];
#pragma unroll
    for (int mi = 0; mi < 4; mi++) {
#pragma unroll
      for (int r = 0; r < 4; r++) {
        const int row = tile_m + wm * 64 + mi * 16 + l4 * 4 + r;
        const size_t idx = (size_t)row * N + col;
        out[idx] = acc[mi][ni][r] + bv + res[idx];
      }
    }
  }
}

// ---------------- Strided-sparse flash attention v3 (unchanged from R9) ----------------
__global__ __launch_bounds__(256, 4) void attn_kernel(const unsigned short* __restrict__ qkv,
                                                      unsigned short* __restrict__ y) {
  __shared__ unsigned short SH[17408];   // 34816 B
  const int tid = threadIdx.x;
  const int lane = tid & 63, w = tid >> 6;
  const int l15 = lane & 15, l4 = lane >> 4;

  const int bi = blockIdx.x;
  const int quarter = bi >> 8, rest = bi & 255;
  const int bh = rest >> 3, sub = rest & 7;
  int qt;
  if (quarter == 0) qt = sub;
  else if (quarter == 1) qt = 15 - sub;
  else if (quarter == 2) qt = 16 + sub;
  else qt = 31 - sub;
  const int bb = bh >> 4, hh = bh & 15;
  const int q0 = qt * 64;
  const size_t base = (size_t)bb * Tn * (3 * Cn) + hh * 64;

  const int nfar = qt >> 1;
  const int ntiles = nfar + (q0 ? 2 : 1);

  unsigned short* Vt = SH + 8192;
  unsigned short* Ps = SH + 12800 + w * 1152;

  auto keyof = [&](int t, int row) -> int {
    if (t < nfar) return t * 128 + 2 * row;
    return q0 - 64 * (ntiles - 1 - t) + row;
  };
  auto stageK = [&](int t) {
    unsigned short* kb = SH + ((t & 1) << 12);
#pragma unroll
    for (int u = 0; u < 2; u++) {
      const int chunk = u * 256 + tid;
      const int row = chunk >> 3, cc = chunk & 7;
      const int csrc = cc ^ (row & 7);
      const int key = keyof(t, row);
      __builtin_amdgcn_global_load_lds(
          (gas_ptr)&qkv[base + Cn + (size_t)key * (3 * Cn) + csrc * 8],
          (las_ptr)&kb[(u * 256 + (w << 6)) * 8], 16, 0, 0);
    }
  };
  uint4 vr[2];
  auto fetchV = [&](int t) {
#pragma unroll
    for (int u = 0; u < 2; u++) {
      const int chunk = u * 256 + tid;
      const int row = chunk >> 3, cc = chunk & 7;
      const int key = keyof(t, row);
      vr[u] = *reinterpret_cast<const uint4*>(&qkv[base + 2 * Cn + (size_t)key * (3 * Cn) + cc * 8]);
    }
  };

#pragma unroll
  for (int u = 0; u < 2; u++) {
    const int chunk = u * 256 + tid;
    const int row = chunk >> 3, cc = chunk & 7;
    const int csrc = cc ^ (row & 7);
    __builtin_amdgcn_global_load_lds(
        (gas_ptr)&qkv[base + (size_t)(q0 + row) * (3 * Cn) + csrc * 8],
        (las_ptr)&SH[(u * 256 + (w << 6)) * 8], 16, 0, 0);
  }
  __syncthreads();
  short8 qf[2];
#pragma unroll
  for (int ks = 0; ks < 2; ks++) {
    const int r = (w << 4) + l15;
    qf[ks] = *reinterpret_cast<const short8*>(&SH[r * 64 + (((ks * 4 + l4) ^ (l15 & 7)) * 8)]);
  }
  asm volatile("s_waitcnt lgkmcnt(0)" ::: "memory");
  __builtin_amdgcn_s_barrier();
  __builtin_amdgcn_sched_barrier(0);
  stageK(0);
  fetchV(0);
  __syncthreads();

  f32x4 acc_o[4] = {};
  float mrow[4], lrow[4];
#pragma unroll
  for (int r = 0; r < 4; r++) { mrow[r] = -1e30f; lrow[r] = 0.0f; }

  for (int t = 0; t < ntiles; ++t) {
#pragma unroll
    for (int u = 0; u < 2; u++) {
      const int chunk = u * 256 + tid;
      const int row = chunk >> 3, cc = chunk & 7;
      unsigned short tmp[8];
      *reinterpret_cast<uint4*>(tmp) = vr[u];
      const int xr = row ^ (cc << 3);
#pragma unroll
      for (int j = 0; j < 8; j++) Vt[(cc * 8 + j) * 72 + xr] = tmp[j];
    }
    if (t + 1 < ntiles) { stageK(t + 1); fetchV(t + 1); }
    asm volatile("s_waitcnt lgkmcnt(0)" ::: "memory");
    __builtin_amdgcn_s_barrier();
    __builtin_amdgcn_sched_barrier(0);

    const unsigned short* Kb = SH + ((t & 1) << 12);
    f32x4 s[4] = {};
#pragma unroll
    for (int ni = 0; ni < 4; ni++) {
#pragma unroll
      for (int ks = 0; ks < 2; ks++) {
        const int r = ni * 16 + l15;
        short8 kf = *reinterpret_cast<const short8*>(&Kb[r * 64 + (((ks * 4 + l4) ^ (l15 & 7)) * 8)]);
        s[ni] = __builtin_amdgcn_mfma_f32_16x16x32_bf16(qf[ks], kf, s[ni], 0, 0, 0);
      }
    }

    const bool far = (t < nfar);
    const int kb0 = far ? t * 128 : q0 - 64 * (ntiles - 1 - t);
#pragma unroll
    for (int ni = 0; ni < 4; ni++) {
      const int pos = ni * 16 + l15;
      const int j = far ? kb0 + 2 * pos : kb0 + pos;
#pragma unroll
      for (int r = 0; r < 4; r++) {
        float v = s[ni][r] * 0.125f;
        if (far) {
          v = (j < q0 - 64) ? v : -1e30f;
        } else {
          const int iq = q0 + (w << 4) + l4 * 4 + r;
          const bool ok = (j <= iq) && ((j >= iq - 4) || ((j & 1) == 0));
          v = ok ? v : -1e30f;
        }
        s[ni][r] = v;
      }
    }

#pragma unroll
    for (int r = 0; r < 4; r++) {
      float tm = fmaxf(fmaxf(s[0][r], s[1][r]), fmaxf(s[2][r], s[3][r]));
      tm = fmaxf(tm, __shfl_xor(tm, 1));
      tm = fmaxf(tm, __shfl_xor(tm, 2));
      tm = fmaxf(tm, __shfl_xor(tm, 4));
      tm = fmaxf(tm, __shfl_xor(tm, 8));
      const float mnew = fmaxf(mrow[r], tm);
      const float alpha = __expf(mrow[r] - mnew);
      mrow[r] = mnew;
      lrow[r] *= alpha;
#pragma unroll
      for (int nd = 0; nd < 4; nd++) acc_o[nd][r] *= alpha;
      float rs = 0.0f;
#pragma unroll
      for (int ni = 0; ni < 4; ni++) {
        const float pv = __expf(s[ni][r] - mnew);
        s[ni][r] = pv;
        rs += pv;
      }
      rs += __shfl_xor(rs, 1); rs += __shfl_xor(rs, 2);
      rs += __shfl_xor(rs, 4); rs += __shfl_xor(rs, 8);
      lrow[r] += rs;
    }

#pragma unroll
    for (int ni = 0; ni < 4; ni++)
#pragma unroll
      for (int r = 0; r < 4; r++)
        Ps[(l4 * 4 + r) * 72 + ni * 16 + l15] = f2b(s[ni][r]);

#pragma unroll
    for (int kss = 0; kss < 2; kss++) {
      short8 pf = *reinterpret_cast<const short8*>(&Ps[l15 * 72 + kss * 32 + l4 * 8]);
#pragma unroll
      for (int nd = 0; nd < 4; nd++) {
        const int d = nd * 16 + l15;
        const int kcol = (kss * 32 + l4 * 8) ^ ((d >> 3) << 3);
        short8 vf = *reinterpret_cast<const short8*>(&Vt[d * 72 + kcol]);
        acc_o[nd] = __builtin_amdgcn_mfma_f32_16x16x32_bf16(pf, vf, acc_o[nd], 0, 0, 0);
      }
    }

    __syncthreads();
  }

#pragma unroll
  for (int r = 0; r < 4; r++) {
    const float inv = 1.0f / lrow[r];
    const int row = q0 + (w << 4) + l4 * 4 + r;
#pragma unroll
    for (int nd = 0; nd < 4; nd++) {
      const int col = nd * 16 + l15;
      y[((size_t)bb * Tn + row) * Cn + hh * 64 + col] = f2b(acc_o[nd][r] * inv);
    }
  }
}

// ---------------- launch ----------------
extern "C" void kernel_launch(void* const* d_in, const int* in_sizes, int n_in,
                              void* d_out, int out_size, void* d_ws, size_t ws_size,
                              hipStream_t stream) {
  const float* x           = (const float*)d_in[0];
  const float* ln1_w       = (const float*)d_in[1];
  const float* ln1_b       = (const float*)d_in[2];
  const float* c_attn_w    = (const float*)d_in[3];
  const float* c_attn_b    = (const float*)d_in[4];
  const float* attn_proj_w = (const float*)d_in[5];
  const float* attn_proj_b = (const float*)d_in[6];
  const float* ln2_w       = (const float*)d_in[7];
  const float* ln2_b       = (const float*)d_in[8];
  const float* fc_w        = (const float*)d_in[9];
  const float* fc_b        = (const float*)d_in[10];
  const float* mlp_proj_w  = (const float*)d_in[11];
  const float* mlp_proj_b  = (const float*)d_in[12];
  float* out = (float*)d_out;

  char* ws = (char*)d_ws;
  unsigned short* wT1 = (unsigned short*)(ws);                     // [3072][1024]
  unsigned short* wT2 = (unsigned short*)(ws + 6291456);           // [1024][1024]
  unsigned short* wT3 = (unsigned short*)(ws + 8388608);           // [4096][1024]
  unsigned short* wT4 = (unsigned short*)(ws + 16777216);          // [1024][4096]
  unsigned short* h   = (unsigned short*)(ws + 25165824);          // [4096][1024]
  unsigned short* qkv = (unsigned short*)(ws + 33554432);          // [4096][3072] / [4096][4096]
  unsigned short* yb  = (unsigned short*)(ws + 67108864);          // [4096][1024]

  hipFuncSetAttribute((const void*)gemm256_kernel<0>, hipFuncAttributeMaxDynamicSharedMemorySize, 131072);
  hipFuncSetAttribute((const void*)gemm256_kernel<2>, hipFuncAttributeMaxDynamicSharedMemorySize, 131072);
  hipFuncSetAttribute((const void*)gemm128_kernel, hipFuncAttributeMaxDynamicSharedMemorySize, 65536);

  transpose_bf16_kernel<<<dim3(3072 / 32, 1024 / 32), 256, 0, stream>>>(c_attn_w, wT1, 1024, 3072);
  transpose_bf16_kernel<<<dim3(1024 / 32, 1024 / 32), 256, 0, stream>>>(attn_proj_w, wT2, 1024, 1024);
  transpose_bf16_kernel<<<dim3(4096 / 32, 1024 / 32), 256, 0, stream>>>(fc_w, wT3, 1024, 4096);
  transpose_bf16_kernel<<<dim3(1024 / 32, 4096 / 32), 256, 0, stream>>>(mlp_proj_w, wT4, 4096, 1024);

  // LN1
  ln_kernel<<<Mrows, 256, 0, stream>>>(x, ln1_w, ln1_b, h);
  // qkv = h @ c_attn_w + b
  gemm256_kernel<0><<<(Mrows / 256) * (3072 / 256), 512, 131072, stream>>>(
      h, wT1, c_attn_b, qkv, Mrows, 3072, 1024, 3072 / 256);
  // attention -> y
  attn_kernel<<<1024, 256, 0, stream>>>(qkv, yb);
  // x1 = x + y @ attn_proj_w + b
  gemm128_kernel<<<(Mrows / 128) * (1024 / 128), 512, 65536, stream>>>(
      yb, wT2, attn_proj_b, x, out, Mrows, 1024, 1024, 1024 / 128);
  // LN2 on x1
  ln_kernel<<<Mrows, 256, 0, stream>>>(out, ln2_w, ln2_b, h);
  // a = gelu(h2 @ fc_w + b)
  gemm256_kernel<2><<<(Mrows / 256) * (4096 / 256), 512, 131072, stream>>>(
      h, wT3, fc_b, qkv, Mrows, 4096, 1024, 4096 / 256);
  // out = x1 + a @ mlp_proj_w + b
  gemm128_kernel<<<(Mrows / 128) * (1024 / 128), 512, 65536, stream>>>(
      qkv, wT4, mlp_proj_b, out, out, Mrows, 1024, 4096, 1024 / 128);
}

// Round 13
// 221.435 us; speedup vs baseline: 1.5900x; 1.0326x over previous
//
#include <hip/hip_runtime.h>
#include <hip/hip_bf16.h>

#define Bn 2
#define Tn 2048
#define Cn 1024
#define Hn 16
#define Dn 64
#define Mrows (Bn * Tn)   // 4096

typedef __attribute__((ext_vector_type(8))) short short8;
typedef __attribute__((ext_vector_type(4))) float f32x4;

typedef const __attribute__((address_space(1))) unsigned int* gas_ptr;
typedef __attribute__((address_space(3))) unsigned int* las_ptr;

__device__ __forceinline__ unsigned short f2b(float f) {
  unsigned int u = __builtin_bit_cast(unsigned int, f);
  return (unsigned short)((u + 0x7fffu + ((u >> 16) & 1u)) >> 16);
}

__device__ __forceinline__ float gelu_f(float v) {
  float u2 = v + 0.044715f * v * v * v;
  float e = __expf(1.5957691216f * u2);
  float th = 1.0f - 2.0f / (e + 1.0f);
  return 0.5f * v * (1.0f + th);
}

// ---------------- LayerNorm row body (shared by ln_kernel and prep_kernel) ----------------
__device__ __forceinline__ void ln_row(const float* __restrict__ x, const float* __restrict__ w,
                                       const float* __restrict__ b, unsigned short* __restrict__ out,
                                       int row, float* ls, float* ls2) {
  const int t = threadIdx.x;
  const float4 v = *reinterpret_cast<const float4*>(x + (size_t)row * Cn + t * 4);
  float s = v.x + v.y + v.z + v.w;
  float s2 = v.x * v.x + v.y * v.y + v.z * v.z + v.w * v.w;
#pragma unroll
  for (int m = 1; m < 64; m <<= 1) { s += __shfl_xor(s, m); s2 += __shfl_xor(s2, m); }
  if ((t & 63) == 0) { ls[t >> 6] = s; ls2[t >> 6] = s2; }
  __syncthreads();
  s  = ls[0] + ls[1] + ls[2] + ls[3];
  s2 = ls2[0] + ls2[1] + ls2[2] + ls2[3];
  const float mu = s * (1.0f / Cn);
  const float rstd = rsqrtf(s2 * (1.0f / Cn) - mu * mu + 1e-5f);
  const float4 wv = *reinterpret_cast<const float4*>(w + t * 4);
  const float4 bv = *reinterpret_cast<const float4*>(b + t * 4);
  unsigned short o[4];
  o[0] = f2b((v.x - mu) * rstd * wv.x + bv.x);
  o[1] = f2b((v.y - mu) * rstd * wv.y + bv.y);
  o[2] = f2b((v.z - mu) * rstd * wv.z + bv.z);
  o[3] = f2b((v.w - mu) * rstd * wv.w + bv.w);
  *reinterpret_cast<uint2*>(out + (size_t)row * Cn + t * 4) = *reinterpret_cast<uint2*>(o);
}

__global__ __launch_bounds__(256) void ln_kernel(const float* __restrict__ x,
                                                 const float* __restrict__ w,
                                                 const float* __restrict__ b,
                                                 unsigned short* __restrict__ out) {
  __shared__ float ls[4], ls2[4];
  ln_row(x, w, b, out, blockIdx.x, ls, ls2);
}

// ---------------- prep: 4 weight transposes (f32->bf16, [K][N]->[N][K]) + LN1 fused ----------------
// blocks 0..12287: transpose segments; 12288..16383: LN1 rows. All independent.
__global__ __launch_bounds__(256) void prep_kernel(
    const float* __restrict__ W0, unsigned short* __restrict__ T0,   // c_attn 1024x3072
    const float* __restrict__ W1, unsigned short* __restrict__ T1,   // attn_proj 1024x1024
    const float* __restrict__ W2, unsigned short* __restrict__ T2,   // fc 1024x4096
    const float* __restrict__ W3, unsigned short* __restrict__ T3,   // mlp 4096x1024
    const float* __restrict__ x, const float* __restrict__ ln1w,
    const float* __restrict__ ln1b, unsigned short* __restrict__ h) {
  __shared__ float tile[32][33];
  __shared__ float ls[4], ls2[4];
  int b = blockIdx.x;
  if (b >= 12288) {
    ln_row(x, ln1w, ln1b, h, b - 12288, ls, ls2);
    return;
  }
  const float* W; unsigned short* T; int K, N;
  if (b < 3072)      { W = W0; T = T0; K = 1024; N = 3072; }
  else if (b < 4096) { W = W1; T = T1; K = 1024; N = 1024; b -= 3072; }
  else if (b < 8192) { W = W2; T = T2; K = 1024; N = 4096; b -= 4096; }
  else               { W = W3; T = T3; K = 4096; N = 1024; b -= 8192; }
  const int nx = N >> 5;
  const int n0 = (b % nx) * 32, k0 = (b / nx) * 32;
  const int tx = threadIdx.x & 31, ty = threadIdx.x >> 5;
#pragma unroll
  for (int r = 0; r < 4; r++)
    tile[ty + r * 8][tx] = W[(size_t)(k0 + ty + r * 8) * N + n0 + tx];
  __syncthreads();
#pragma unroll
  for (int r = 0; r < 4; r++)
    T[(size_t)(n0 + ty + r * 8) * K + k0 + tx] = f2b(tile[tx][ty + r * 8]);
}

// ---------------- 256^2 8-wave pipelined GEMM — R12 slim-sync (unchanged) ----------------
#define BUFS 16384
template <int EP>
__global__ __launch_bounds__(512, 2) void gemm256_kernel(
    const unsigned short* __restrict__ A, const unsigned short* __restrict__ Bt,
    const float* __restrict__ bias, void* out, int M, int N, int K, int nx) {
  extern __shared__ unsigned short lds[];
  const int tid = threadIdx.x;
  const int lane = tid & 63, w = tid >> 6;
  const int wm = w >> 2, wn = w & 3;
  const int l15 = lane & 15, l4 = lane >> 4;

  const int nwg = gridDim.x;
  int wg = blockIdx.x;
  wg = (wg & 7) * (nwg >> 3) + (wg >> 3);
  const int tile_m = (wg / nx) * 256;
  const int tile_n = (wg % nx) * 256;

  f32x4 acc[8][4] = {};

  const int ch0 = w * 64 + lane;
  const int r0 = ch0 >> 2;
  const int c0 = (((ch0 & 3) ^ ((r0 >> 1) & 3))) * 8;
  const unsigned short* gA0 = A + (size_t)(tile_m + r0) * K + c0;
  const unsigned short* gA1 = gA0 + (size_t)128 * K;
  const unsigned short* gB0 = Bt + (size_t)(tile_n + r0) * K + c0;
  const unsigned short* gB1 = gB0 + (size_t)128 * K;
  const int ldsA0 = (w * 64) * 8, ldsA1 = (512 + w * 64) * 8;

  auto stage = [&](unsigned short* Ab, int t) {
    unsigned short* Bb = Ab + 8192;
    const size_t ko = (size_t)t * 32;
    __builtin_amdgcn_global_load_lds((gas_ptr)(gA0 + ko), (las_ptr)&Ab[ldsA0], 16, 0, 0);
    __builtin_amdgcn_global_load_lds((gas_ptr)(gA1 + ko), (las_ptr)&Ab[ldsA1], 16, 0, 0);
    __builtin_amdgcn_global_load_lds((gas_ptr)(gB0 + ko), (las_ptr)&Bb[ldsA0], 16, 0, 0);
    __builtin_amdgcn_global_load_lds((gas_ptr)(gB1 + ko), (las_ptr)&Bb[ldsA1], 16, 0, 0);
  };

  stage(lds, 0);
  stage(lds + BUFS, 1);
  stage(lds + 2 * BUFS, 2);
  asm volatile("s_waitcnt vmcnt(8)" ::: "memory");
  __builtin_amdgcn_s_barrier();
  __builtin_amdgcn_sched_barrier(0);

  const int ca = (l4 ^ ((l15 >> 1) & 3)) * 8;

  const int nt = K >> 5;
  for (int tb = 0; tb < nt; tb += 4) {
#pragma unroll
    for (int u = 0; u < 4; u++) {
      const int t = tb + u;
      if (t + 3 < nt) stage(lds + (((u + 3) & 3) * BUFS), t + 3);

      const unsigned short* Ab = lds + u * BUFS;
      const unsigned short* Bb = Ab + 8192;
      short8 a[4], b[4], a2[4];
#pragma unroll
      for (int i = 0; i < 4; i++) {
        a[i] = *reinterpret_cast<const short8*>(&Ab[(wm * 128 + i * 16 + l15) * 32 + ca]);
        b[i] = *reinterpret_cast<const short8*>(&Bb[(wn * 64 + i * 16 + l15) * 32 + ca]);
      }
      __builtin_amdgcn_sched_barrier(0);
#pragma unroll
      for (int i = 0; i < 4; i++)
        a2[i] = *reinterpret_cast<const short8*>(&Ab[(wm * 128 + 64 + i * 16 + l15) * 32 + ca]);

      asm volatile("s_waitcnt lgkmcnt(4)" ::: "memory");
      __builtin_amdgcn_sched_barrier(0);
      __builtin_amdgcn_s_setprio(1);
#pragma unroll
      for (int mi = 0; mi < 4; mi++)
#pragma unroll
        for (int ni = 0; ni < 4; ni++)
          acc[mi][ni] = __builtin_amdgcn_mfma_f32_16x16x32_bf16(a[mi], b[ni], acc[mi][ni], 0, 0, 0);
      __builtin_amdgcn_s_setprio(0);
      __builtin_amdgcn_sched_barrier(0);

      asm volatile("s_waitcnt lgkmcnt(0)" ::: "memory");
      __builtin_amdgcn_sched_barrier(0);
      __builtin_amdgcn_s_setprio(1);
#pragma unroll
      for (int mi = 0; mi < 4; mi++)
#pragma unroll
        for (int ni = 0; ni < 4; ni++)
          acc[mi + 4][ni] = __builtin_amdgcn_mfma_f32_16x16x32_bf16(a2[mi], b[ni], acc[mi + 4][ni], 0, 0, 0);
      __builtin_amdgcn_s_setprio(0);
      __builtin_amdgcn_sched_barrier(0);

      if (t + 3 < nt) {
        asm volatile("s_waitcnt vmcnt(8)" ::: "memory");
      } else if (t + 2 < nt) {
        asm volatile("s_waitcnt vmcnt(4)" ::: "memory");
      } else if (t + 1 < nt) {
        asm volatile("s_waitcnt vmcnt(0)" ::: "memory");
      }
      __builtin_amdgcn_s_barrier();
      __builtin_amdgcn_sched_barrier(0);
    }
  }

#pragma unroll
  for (int ni = 0; ni < 4; ni++) {
    const int col = tile_n + wn * 64 + ni * 16 + l15;
    const float bv = bias[col];
#pragma unroll
    for (int mi = 0; mi < 8; mi++) {
#pragma unroll
      for (int r = 0; r < 4; r++) {
        const int row = tile_m + wm * 128 + mi * 16 + l4 * 4 + r;
        const size_t idx = (size_t)row * N + col;
        float v = acc[mi][ni][r] + bv;
        if (EP == 0) {
          ((unsigned short*)out)[idx] = f2b(v);
        } else {
          ((unsigned short*)out)[idx] = f2b(gelu_f(v));
        }
      }
    }
  }
}

// ---------------- 128^2 GEMM — R13 pair-processing (2 K-tiles per barrier) ----------------
// Ring-6 slots (96 KB). Pair p reads slots (2p%6, 2p+1%6); stages pair p+2 (slot
// reuse distance 3 pairs: reads done 2 barriers earlier => WAR safe). End-of-pair
// counted vmcnt(4): pair p+1 landed, pair p+2 (4 loads) stays in flight; barrier
// publishes. nt even at all call sites. EP: f32 out = v + bias + res (res may
// alias out: read-once-write-once per idx by one thread).
__global__ __launch_bounds__(512, 1) void gemm128_kernel(
    const unsigned short* __restrict__ A, const unsigned short* __restrict__ Bt,
    const float* __restrict__ bias, const float* __restrict__ res, float* __restrict__ out,
    int M, int N, int K, int nx) {
  extern __shared__ unsigned short lds[];
  const int tid = threadIdx.x;
  const int lane = tid & 63, w = tid >> 6;
  const int wm = w >> 2, wn = w & 3;
  const int l15 = lane & 15, l4 = lane >> 4;

  const int nwg = gridDim.x;
  int wg = blockIdx.x;
  wg = (wg & 7) * (nwg >> 3) + (wg >> 3);
  const int tile_m = (wg / nx) * 128;
  const int tile_n = (wg % nx) * 128;

  f32x4 acc[4][2] = {};

  const unsigned short* Gs = (w < 4) ? A : Bt;
  const int tb0 = (w < 4) ? tile_m : tile_n;
  const int ch0 = (w & 3) * 128 + lane;
  const int r0c = ch0 >> 2;
  const int c0s = (((ch0 & 3) ^ ((r0c >> 1) & 3))) * 8;
  const unsigned short* g0 = Gs + (size_t)(tb0 + r0c) * K + c0s;
  const unsigned short* g1 = g0 + (size_t)16 * K;
  const int lds0 = ((w & 3) * 128) * 8, lds1 = ((w & 3) * 128 + 64) * 8;
  const int half = (w < 4) ? 0 : 4096;

  auto stage = [&](int slot, int t) {
    unsigned short* Lb = lds + slot * 8192 + half;
    const size_t ko = (size_t)t * 32;
    __builtin_amdgcn_global_load_lds((gas_ptr)(g0 + ko), (las_ptr)&Lb[lds0], 16, 0, 0);
    __builtin_amdgcn_global_load_lds((gas_ptr)(g1 + ko), (las_ptr)&Lb[lds1], 16, 0, 0);
  };

  stage(0, 0);
  stage(1, 1);
  stage(2, 2);
  stage(3, 3);
  asm volatile("s_waitcnt vmcnt(4)" ::: "memory");   // tiles 0,1 landed; 2,3 in flight
  __builtin_amdgcn_s_barrier();
  __builtin_amdgcn_sched_barrier(0);

  const int ca = (l4 ^ ((l15 >> 1) & 3)) * 8;

  const int nt = K >> 5;        // even (32 or 128)
  const int np = nt >> 1;
  for (int p = 0; p < np; ++p) {
    const int t0 = 2 * p;
    if (t0 + 4 < nt) stage((t0 + 4) % 6, t0 + 4);
    if (t0 + 5 < nt) stage((t0 + 5) % 6, t0 + 5);

    const unsigned short* A0 = lds + (t0 % 6) * 8192;
    const unsigned short* B0 = A0 + 4096;
    const unsigned short* A1 = lds + ((t0 + 1) % 6) * 8192;
    const unsigned short* B1 = A1 + 4096;
    short8 a[2], b[2], a2[2], c[2], d[2], c2[2];
#pragma unroll
    for (int i = 0; i < 2; i++) {
      a[i] = *reinterpret_cast<const short8*>(&A0[(wm * 64 + i * 16 + l15) * 32 + ca]);
      b[i] = *reinterpret_cast<const short8*>(&B0[(wn * 32 + i * 16 + l15) * 32 + ca]);
    }
    __builtin_amdgcn_sched_barrier(0);
#pragma unroll
    for (int i = 0; i < 2; i++)
      a2[i] = *reinterpret_cast<const short8*>(&A0[(wm * 64 + 32 + i * 16 + l15) * 32 + ca]);
    __builtin_amdgcn_sched_barrier(0);
#pragma unroll
    for (int i = 0; i < 2; i++) {
      c[i] = *reinterpret_cast<const short8*>(&A1[(wm * 64 + i * 16 + l15) * 32 + ca]);
      d[i] = *reinterpret_cast<const short8*>(&B1[(wn * 32 + i * 16 + l15) * 32 + ca]);
    }
    __builtin_amdgcn_sched_barrier(0);
#pragma unroll
    for (int i = 0; i < 2; i++)
      c2[i] = *reinterpret_cast<const short8*>(&A1[(wm * 64 + 32 + i * 16 + l15) * 32 + ca]);

    asm volatile("s_waitcnt lgkmcnt(8)" ::: "memory");   // a,b ready
    __builtin_amdgcn_sched_barrier(0);
    __builtin_amdgcn_s_setprio(1);
#pragma unroll
    for (int mi = 0; mi < 2; mi++)
#pragma unroll
      for (int ni = 0; ni < 2; ni++)
        acc[mi][ni] = __builtin_amdgcn_mfma_f32_16x16x32_bf16(a[mi], b[ni], acc[mi][ni], 0, 0, 0);
    __builtin_amdgcn_s_setprio(0);
    __builtin_amdgcn_sched_barrier(0);

    asm volatile("s_waitcnt lgkmcnt(6)" ::: "memory");   // a2 ready
    __builtin_amdgcn_sched_barrier(0);
    __builtin_amdgcn_s_setprio(1);
#pragma unroll
    for (int mi = 0; mi < 2; mi++)
#pragma unroll
      for (int ni = 0; ni < 2; ni++)
        acc[mi + 2][ni] = __builtin_amdgcn_mfma_f32_16x16x32_bf16(a2[mi], b[ni], acc[mi + 2][ni], 0, 0, 0);
    __builtin_amdgcn_s_setprio(0);
    __builtin_amdgcn_sched_barrier(0);

    asm volatile("s_waitcnt lgkmcnt(2)" ::: "memory");   // c,d ready
    __builtin_amdgcn_sched_barrier(0);
    __builtin_amdgcn_s_setprio(1);
#pragma unroll
    for (int mi = 0; mi < 2; mi++)
#pragma unroll
      for (int ni = 0; ni < 2; ni++)
        acc[mi][ni] = __builtin_amdgcn_mfma_f32_16x16x32_bf16(c[mi], d[ni], acc[mi][ni], 0, 0, 0);
    __builtin_amdgcn_s_setprio(0);
    __builtin_amdgcn_sched_barrier(0);

    asm volatile("s_waitcnt lgkmcnt(0)" ::: "memory");   // c2 ready
    __builtin_amdgcn_sched_barrier(0);
    __builtin_amdgcn_s_setprio(1);
#pragma unroll
    for (int mi = 0; mi < 2; mi++)
#pragma unroll
      for (int ni = 0; ni < 2; ni++)
        acc[mi + 2][ni] = __builtin_amdgcn_mfma_f32_16x16x32_bf16(c2[mi], d[ni], acc[mi + 2][ni], 0, 0, 0);
    __builtin_amdgcn_s_setprio(0);
    __builtin_amdgcn_sched_barrier(0);

    if (t0 + 4 < nt) {
      asm volatile("s_waitcnt vmcnt(4)" ::: "memory");   // pair p+1 landed
    } else if (t0 + 2 < nt) {
      asm volatile("s_waitcnt vmcnt(0)" ::: "memory");   // last pair: drain
    }
    __builtin_amdgcn_s_barrier();
    __builtin_amdgcn_sched_barrier(0);
  }

#pragma unroll
  for (int ni = 0; ni < 2; ni++) {
    const int col = tile_n + wn * 32 + ni * 16 + l15;
    const float bv = bias[col];
#pragma unroll
    for (int mi = 0; mi < 4; mi++) {
#pragma unroll
      for (int r = 0; r < 4; r++) {
        const int row = tile_m + wm * 64 + mi * 16 + l4 * 4 + r;
        const size_t idx = (size_t)row * N + col;
        out[idx] = acc[mi][ni][r] + bv + res[idx];
      }
    }
  }
}

// ---------------- Strided-sparse flash attention v3 + T13 defer-max ----------------
__global__ __launch_bounds__(256, 4) void attn_kernel(const unsigned short* __restrict__ qkv,
                                                      unsigned short* __restrict__ y) {
  __shared__ unsigned short SH[17408];   // 34816 B
  const int tid = threadIdx.x;
  const int lane = tid & 63, w = tid >> 6;
  const int l15 = lane & 15, l4 = lane >> 4;

  const int bi = blockIdx.x;
  const int quarter = bi >> 8, rest = bi & 255;
  const int bh = rest >> 3, sub = rest & 7;
  int qt;
  if (quarter == 0) qt = sub;
  else if (quarter == 1) qt = 15 - sub;
  else if (quarter == 2) qt = 16 + sub;
  else qt = 31 - sub;
  const int bb = bh >> 4, hh = bh & 15;
  const int q0 = qt * 64;
  const size_t base = (size_t)bb * Tn * (3 * Cn) + hh * 64;

  const int nfar = qt >> 1;
  const int ntiles = nfar + (q0 ? 2 : 1);

  unsigned short* Vt = SH + 8192;
  unsigned short* Ps = SH + 12800 + w * 1152;

  auto keyof = [&](int t, int row) -> int {
    if (t < nfar) return t * 128 + 2 * row;
    return q0 - 64 * (ntiles - 1 - t) + row;
  };
  auto stageK = [&](int t) {
    unsigned short* kb = SH + ((t & 1) << 12);
#pragma unroll
    for (int u = 0; u < 2; u++) {
      const int chunk = u * 256 + tid;
      const int row = chunk >> 3, cc = chunk & 7;
      const int csrc = cc ^ (row & 7);
      const int key = keyof(t, row);
      __builtin_amdgcn_global_load_lds(
          (gas_ptr)&qkv[base + Cn + (size_t)key * (3 * Cn) + csrc * 8],
          (las_ptr)&kb[(u * 256 + (w << 6)) * 8], 16, 0, 0);
    }
  };
  uint4 vr[2];
  auto fetchV = [&](int t) {
#pragma unroll
    for (int u = 0; u < 2; u++) {
      const int chunk = u * 256 + tid;
      const int row = chunk >> 3, cc = chunk & 7;
      const int key = keyof(t, row);
      vr[u] = *reinterpret_cast<const uint4*>(&qkv[base + 2 * Cn + (size_t)key * (3 * Cn) + cc * 8]);
    }
  };

#pragma unroll
  for (int u = 0; u < 2; u++) {
    const int chunk = u * 256 + tid;
    const int row = chunk >> 3, cc = chunk & 7;
    const int csrc = cc ^ (row & 7);
    __builtin_amdgcn_global_load_lds(
        (gas_ptr)&qkv[base + (size_t)(q0 + row) * (3 * Cn) + csrc * 8],
        (las_ptr)&SH[(u * 256 + (w << 6)) * 8], 16, 0, 0);
  }
  __syncthreads();
  short8 qf[2];
#pragma unroll
  for (int ks = 0; ks < 2; ks++) {
    const int r = (w << 4) + l15;
    qf[ks] = *reinterpret_cast<const short8*>(&SH[r * 64 + (((ks * 4 + l4) ^ (l15 & 7)) * 8)]);
  }
  asm volatile("s_waitcnt lgkmcnt(0)" ::: "memory");
  __builtin_amdgcn_s_barrier();
  __builtin_amdgcn_sched_barrier(0);
  stageK(0);
  fetchV(0);
  __syncthreads();

  f32x4 acc_o[4] = {};
  float mrow[4], lrow[4];
#pragma unroll
  for (int r = 0; r < 4; r++) { mrow[r] = -1e30f; lrow[r] = 0.0f; }

  for (int t = 0; t < ntiles; ++t) {
#pragma unroll
    for (int u = 0; u < 2; u++) {
      const int chunk = u * 256 + tid;
      const int row = chunk >> 3, cc = chunk & 7;
      unsigned short tmp[8];
      *reinterpret_cast<uint4*>(tmp) = vr[u];
      const int xr = row ^ (cc << 3);
#pragma unroll
      for (int j = 0; j < 8; j++) Vt[(cc * 8 + j) * 72 + xr] = tmp[j];
    }
    if (t + 1 < ntiles) { stageK(t + 1); fetchV(t + 1); }
    asm volatile("s_waitcnt lgkmcnt(0)" ::: "memory");
    __builtin_amdgcn_s_barrier();
    __builtin_amdgcn_sched_barrier(0);

    const unsigned short* Kb = SH + ((t & 1) << 12);
    f32x4 s[4] = {};
#pragma unroll
    for (int ni = 0; ni < 4; ni++) {
#pragma unroll
      for (int ks = 0; ks < 2; ks++) {
        const int r = ni * 16 + l15;
        short8 kf = *reinterpret_cast<const short8*>(&Kb[r * 64 + (((ks * 4 + l4) ^ (l15 & 7)) * 8)]);
        s[ni] = __builtin_amdgcn_mfma_f32_16x16x32_bf16(qf[ks], kf, s[ni], 0, 0, 0);
      }
    }

    const bool far = (t < nfar);
    const int kb0 = far ? t * 128 : q0 - 64 * (ntiles - 1 - t);
#pragma unroll
    for (int ni = 0; ni < 4; ni++) {
      const int pos = ni * 16 + l15;
      const int j = far ? kb0 + 2 * pos : kb0 + pos;
#pragma unroll
      for (int r = 0; r < 4; r++) {
        float v = s[ni][r] * 0.125f;
        if (far) {
          v = (j < q0 - 64) ? v : -1e30f;
        } else {
          const int iq = q0 + (w << 4) + l4 * 4 + r;
          const bool ok = (j <= iq) && ((j >= iq - 4) || ((j & 1) == 0));
          v = ok ? v : -1e30f;
        }
        s[ni][r] = v;
      }
    }

    // T13 defer-max: skip the O/l rescale when tile max growth <= 8 (P bounded by e^8)
    float tmx[4];
    bool need = false;
#pragma unroll
    for (int r = 0; r < 4; r++) {
      float tm = fmaxf(fmaxf(s[0][r], s[1][r]), fmaxf(s[2][r], s[3][r]));
      tm = fmaxf(tm, __shfl_xor(tm, 1));
      tm = fmaxf(tm, __shfl_xor(tm, 2));
      tm = fmaxf(tm, __shfl_xor(tm, 4));
      tm = fmaxf(tm, __shfl_xor(tm, 8));
      tmx[r] = tm;
      need = need || (tm > mrow[r] + 8.0f);
    }
    if (__any(need)) {
#pragma unroll
      for (int r = 0; r < 4; r++) {
        const float mnew = fmaxf(mrow[r], tmx[r]);
        const float alpha = __expf(mrow[r] - mnew);
        mrow[r] = mnew;
        lrow[r] *= alpha;
#pragma unroll
        for (int nd = 0; nd < 4; nd++) acc_o[nd][r] *= alpha;
      }
    }
#pragma unroll
    for (int r = 0; r < 4; r++) {
      float rs = 0.0f;
#pragma unroll
      for (int ni = 0; ni < 4; ni++) {
        const float pv = __expf(s[ni][r] - mrow[r]);
        s[ni][r] = pv;
        rs += pv;
      }
      rs += __shfl_xor(rs, 1); rs += __shfl_xor(rs, 2);
      rs += __shfl_xor(rs, 4); rs += __shfl_xor(rs, 8);
      lrow[r] += rs;
    }

#pragma unroll
    for (int ni = 0; ni < 4; ni++)
#pragma unroll
      for (int r = 0; r < 4; r++)
        Ps[(l4 * 4 + r) * 72 + ni * 16 + l15] = f2b(s[ni][r]);

#pragma unroll
    for (int kss = 0; kss < 2; kss++) {
      short8 pf = *reinterpret_cast<const short8*>(&Ps[l15 * 72 + kss * 32 + l4 * 8]);
#pragma unroll
      for (int nd = 0; nd < 4; nd++) {
        const int d = nd * 16 + l15;
        const int kcol = (kss * 32 + l4 * 8) ^ ((d >> 3) << 3);
        short8 vf = *reinterpret_cast<const short8*>(&Vt[d * 72 + kcol]);
        acc_o[nd] = __builtin_amdgcn_mfma_f32_16x16x32_bf16(pf, vf, acc_o[nd], 0, 0, 0);
      }
    }

    __syncthreads();
  }

#pragma unroll
  for (int r = 0; r < 4; r++) {
    const float inv = 1.0f / lrow[r];
    const int row = q0 + (w << 4) + l4 * 4 + r;
#pragma unroll
    for (int nd = 0; nd < 4; nd++) {
      const int col = nd * 16 + l15;
      y[((size_t)bb * Tn + row) * Cn + hh * 64 + col] = f2b(acc_o[nd][r] * inv);
    }
  }
}

// ---------------- launch ----------------
extern "C" void kernel_launch(void* const* d_in, const int* in_sizes, int n_in,
                              void* d_out, int out_size, void* d_ws, size_t ws_size,
                              hipStream_t stream) {
  const float* x           = (const float*)d_in[0];
  const float* ln1_w       = (const float*)d_in[1];
  const float* ln1_b       = (const float*)d_in[2];
  const float* c_attn_w    = (const float*)d_in[3];
  const float* c_attn_b    = (const float*)d_in[4];
  const float* attn_proj_w = (const float*)d_in[5];
  const float* attn_proj_b = (const float*)d_in[6];
  const float* ln2_w       = (const float*)d_in[7];
  const float* ln2_b       = (const float*)d_in[8];
  const float* fc_w        = (const float*)d_in[9];
  const float* fc_b        = (const float*)d_in[10];
  const float* mlp_proj_w  = (const float*)d_in[11];
  const float* mlp_proj_b  = (const float*)d_in[12];
  float* out = (float*)d_out;

  char* ws = (char*)d_ws;
  unsigned short* wT1 = (unsigned short*)(ws);                     // [3072][1024]
  unsigned short* wT2 = (unsigned short*)(ws + 6291456);           // [1024][1024]
  unsigned short* wT3 = (unsigned short*)(ws + 8388608);           // [4096][1024]
  unsigned short* wT4 = (unsigned short*)(ws + 16777216);          // [1024][4096]
  unsigned short* h   = (unsigned short*)(ws + 25165824);          // [4096][1024]
  unsigned short* qkv = (unsigned short*)(ws + 33554432);          // [4096][3072] / [4096][4096]
  unsigned short* yb  = (unsigned short*)(ws + 67108864);          // [4096][1024]

  hipFuncSetAttribute((const void*)gemm256_kernel<0>, hipFuncAttributeMaxDynamicSharedMemorySize, 131072);
  hipFuncSetAttribute((const void*)gemm256_kernel<2>, hipFuncAttributeMaxDynamicSharedMemorySize, 131072);
  hipFuncSetAttribute((const void*)gemm128_kernel, hipFuncAttributeMaxDynamicSharedMemorySize, 98304);

  // prep: 4 transposes + LN1 in one launch (all independent)
  prep_kernel<<<16384, 256, 0, stream>>>(c_attn_w, wT1, attn_proj_w, wT2,
                                         fc_w, wT3, mlp_proj_w, wT4,
                                         x, ln1_w, ln1_b, h);
  // qkv = h @ c_attn_w + b
  gemm256_kernel<0><<<(Mrows / 256) * (3072 / 256), 512, 131072, stream>>>(
      h, wT1, c_attn_b, qkv, Mrows, 3072, 1024, 3072 / 256);
  // attention -> y
  attn_kernel<<<1024, 256, 0, stream>>>(qkv, yb);
  // x1 = x + y @ attn_proj_w + b
  gemm128_kernel<<<(Mrows / 128) * (1024 / 128), 512, 98304, stream>>>(
      yb, wT2, attn_proj_b, x, out, Mrows, 1024, 1024, 1024 / 128);
  // LN2 on x1
  ln_kernel<<<Mrows, 256, 0, stream>>>(out, ln2_w, ln2_b, h);
  // a = gelu(h2 @ fc_w + b)
  gemm256_kernel<2><<<(Mrows / 256) * (4096 / 256), 512, 131072, stream>>>(
      h, wT3, fc_b, qkv, Mrows, 4096, 1024, 4096 / 256);
  // out = x1 + a @ mlp_proj_w + b
  gemm128_kernel<<<(Mrows / 128) * (1024 / 128), 512, 98304, stream>>>(
      qkv, wT4, mlp_proj_b, out, out, Mrows, 1024, 4096, 1024 / 128);
}